// Round 6
// baseline (238.825 us; speedup 1.0000x reference)
//
#include <hip/hip_runtime.h>
#include <cstdint>

typedef __attribute__((ext_vector_type(8))) _Float16 f16x8;
typedef __attribute__((ext_vector_type(4))) float f32x4;

#define DEV static __device__ __forceinline__

DEV void gld_lds16(void* lds_base, const void* gsrc) {
  __builtin_amdgcn_global_load_lds(
      (const __attribute__((address_space(1))) unsigned int*)gsrc,
      (__attribute__((address_space(3))) unsigned int*)lds_base,
      16, 0, 0);
}
DEV unsigned short f2h(float f) {
  _Float16 h = (_Float16)f;
  return __builtin_bit_cast(unsigned short, h);
}
DEV float h2f(unsigned short u) {
  _Float16 h = __builtin_bit_cast(_Float16, u);
  return (float)h;
}
DEV unsigned pk2h(float a, float b) {
  auto h2 = __builtin_amdgcn_cvt_pkrtz(a, b);
  return __builtin_bit_cast(unsigned, h2);
}
DEV float v_exp2(float x) { float r; asm("v_exp_f32 %0, %1" : "=v"(r) : "v"(x)); return r; }
DEV float v_rcp(float x) { float r; asm("v_rcp_f32 %0, %1" : "=v"(r) : "v"(x)); return r; }

// ---------------- geometry ----------------
// B=4, C=256, H=W=64, N=4096, heads=2, hd=128
// ws layout (bytes):
//   Xpad [4][74][74][256] f16 : 0        .. 11214848   (reused as O1 f16 [8][128][4096] during attn)
//   Wq [3][3][256][256] f16   : 11214848 .. 12394496   (reused as ml buf [2][8][4096][2] f32 during attn)
//   Wk [256][256] f16         : 12394496 .. 12525568
//   Wv [256][256] f16         : 12525568 .. 12656640
//   Q  [8][4096][128] f16     : 12656640 .. 21045248   (pre-scaled by log2e/sqrt(128))
//   K  [8][4096][128] f16     : 21045248 .. 29433856
//   V  [8][128][4096] f16     : 29433856 .. 37822464   (m-permuted per 64-block: s=[m5,m3,m2,m4,m1,m0])

// ---------- prep: x (f32 NCHW) -> Xpad (f16, pixel-major, halo 5) ----------
__global__ __launch_bounds__(256) void k_prep_x(const float* __restrict__ x, char* __restrict__ xpad) {
  __shared__ float xs[32 * 257];
  int h = blockIdx.x, b = blockIdx.y, t = threadIdx.x;
  const float* xb = x + (size_t)b * 1048576 + h * 64;
  for (int half = 0; half < 2; half++) {
    int w0 = half * 32;
    for (int kk = 0; kk < 32; kk++) {
      int flat = kk * 256 + t;       // ci*32 + w
      int ci = flat >> 5, w = flat & 31;
      xs[w * 257 + ci] = xb[ci * 4096 + w0 + w];
    }
    __syncthreads();
    for (int g = 0; g < 4; g++) {
      int w = g * 8 + (t >> 5);
      int cg = t & 31;               // 8-ci chunk
      float v0 = xs[w * 257 + cg * 8 + 0], v1 = xs[w * 257 + cg * 8 + 1];
      float v2 = xs[w * 257 + cg * 8 + 2], v3 = xs[w * 257 + cg * 8 + 3];
      float v4 = xs[w * 257 + cg * 8 + 4], v5 = xs[w * 257 + cg * 8 + 5];
      float v6 = xs[w * 257 + cg * 8 + 6], v7 = xs[w * 257 + cg * 8 + 7];
      uint4 pk;
      pk.x = pk2h(v0, v1);
      pk.y = pk2h(v2, v3);
      pk.z = pk2h(v4, v5);
      pk.w = pk2h(v6, v7);
      *(uint4*)(xpad + ((size_t)((b * 74 + h + 5) * 74) + w0 + w + 5) * 512 + cg * 16) = pk;
    }
    __syncthreads();
  }
}

// ---------- prep: weights -> f16 ----------
__global__ __launch_bounds__(256) void k_prep_w(
    const float* __restrict__ qw, const float* __restrict__ kw, const float* __restrict__ vw,
    unsigned short* __restrict__ Wq, unsigned short* __restrict__ Wk, unsigned short* __restrict__ Wv) {
  int gid = blockIdx.x * 256 + threadIdx.x;   // co*256+ci
  const float* q9 = qw + (size_t)gid * 9;
#pragma unroll
  for (int tp = 0; tp < 9; tp++) Wq[tp * 65536 + gid] = f2h(q9[tp]);
  Wk[gid] = f2h(kw[gid]);
  Wv[gid] = f2h(vw[gid]);
}

// ---------- 1x1 convs: K[bh][m][d], V[bh][d][s(m)] ----------
__global__ __launch_bounds__(256, 2) void k_conv_kv(
    const char* __restrict__ xpad, const unsigned short* __restrict__ Wk,
    const unsigned short* __restrict__ Wv, const float* __restrict__ kb,
    const float* __restrict__ vb, unsigned short* __restrict__ K, unsigned short* __restrict__ V) {
  __shared__ char sm[32768];
  char* Xs = sm;
  char* Ws = sm + 16384;
  int t = threadIdx.x, lane = t & 63, wid = t >> 6, q4 = lane >> 4, l15 = lane & 15;
  int px0 = blockIdx.x * 128;
  int b = px0 >> 12, nn = px0 & 4095;
  int h = blockIdx.y;          // co half / head
  int mode = blockIdx.z;       // 0: K (D[px][co]),  1: V (D[co][px])
  int co0 = h * 128;
  const char* Wsrc = (const char*)(mode ? Wv : Wk);
  int wm = wid & 1, wn = wid >> 1;
  f32x4 acc[4][4] = {};
  for (int c = 0; c < 4; c++) {
    __syncthreads();
    for (int ch = wid * 1024; ch < 16384; ch += 4096) {   // X tile [128px][64ci]
      int o = ch + lane * 16;
      int r = o >> 7;
      int n = nn + r, hh = n >> 6, ww2 = n & 63;
      int col = (o & 127) ^ ((r & 7) << 4);
      gld_lds16(Xs + ch, xpad + ((size_t)((b * 74 + hh + 5) * 74) + ww2 + 5) * 512 + c * 128 + col);
    }
    for (int ch = wid * 1024; ch < 16384; ch += 4096) {   // W tile [128co][64ci]
      int o = ch + lane * 16;
      int r = o >> 7;
      int col = (o & 127) ^ ((r & 7) << 4);
      gld_lds16(Ws + ch, Wsrc + (co0 + r) * 512 + c * 128 + col);
    }
    asm volatile("s_waitcnt vmcnt(0)" ::: "memory");
    __syncthreads();
    int xg = mode ? wn : wm;   // X-frag 64-row group
    int wg = mode ? wm : wn;   // W-frag 64-row group
#pragma unroll
    for (int kt = 0; kt < 2; kt++) {
      f16x8 xf[4], wf[4];
#pragma unroll
      for (int i = 0; i < 4; i++) {
        int rx = xg * 64 + i * 16 + l15;
        xf[i] = *(const f16x8*)(Xs + ((rx * 128 + kt * 64 + q4 * 16) ^ ((rx & 7) << 4)));
        int rw = wg * 64 + i * 16 + l15;
        wf[i] = *(const f16x8*)(Ws + ((rw * 128 + kt * 64 + q4 * 16) ^ ((rw & 7) << 4)));
      }
#pragma unroll
      for (int m = 0; m < 4; m++)
#pragma unroll
        for (int n = 0; n < 4; n++)
          acc[m][n] = mode ? __builtin_amdgcn_mfma_f32_16x16x32_f16(wf[m], xf[n], acc[m][n], 0, 0, 0)
                           : __builtin_amdgcn_mfma_f32_16x16x32_f16(xf[m], wf[n], acc[m][n], 0, 0, 0);
    }
  }
  int bh = b * 2 + h;
  if (mode == 0) {
#pragma unroll
    for (int m = 0; m < 4; m++)
#pragma unroll
      for (int n = 0; n < 4; n++) {
        int dd = wn * 64 + n * 16 + l15;
        float bias = kb[co0 + dd];
#pragma unroll
        for (int j = 0; j < 4; j++) {
          int npix = nn + wm * 64 + m * 16 + q4 * 4 + j;
          K[(size_t)(bh * 4096 + npix) * 128 + dd] = f2h(acc[m][n][j] + bias);
        }
      }
  } else {
#pragma unroll
    for (int m = 0; m < 4; m++)
#pragma unroll
      for (int j = 0; j < 4; j++) {
        int cr = wm * 64 + m * 16 + q4 * 4 + j;
        float bias = vb[co0 + cr];
#pragma unroll
        for (int n = 0; n < 4; n++) {
          // m-permuted storage within each 64-block: m_local = n*16 + l15
          // -> s = (n>>1)*32 + (l15>>2)*8 + (n&1)*4 + (l15&3)
          int pc = nn + wn * 64 + (n >> 1) * 32 + (l15 >> 2) * 8 + (n & 1) * 4 + (l15 & 3);
          V[(size_t)(bh * 128 + cr) * 4096 + pc] = f2h(acc[m][n][j] + bias);
        }
      }
  }
}

// ---------- dilated 3x3 conv sum(SiLU) -> Q[bh][n][d] ----------
// 1D grid 512, XCD swizzle: each XCD owns one (b, ch2) pair (X batch + W half L2-resident)
__global__ __launch_bounds__(256, 2) void k_conv_q(
    const char* __restrict__ xpad, const unsigned short* __restrict__ Wq,
    const float* __restrict__ qb, unsigned short* __restrict__ Q) {
  extern __shared__ char sm[];
  char* Bs = sm;               // [3 kw][128 co][64 ci] f16 = 49152
  char* As = sm + 49152;       // 3 x [74 w][64 ci] f16 (pitch 10240)
  int t = threadIdx.x, lane = t & 63, wid = t >> 6, q4 = lane >> 4, l15 = lane & 15;
  int fblk = blockIdx.x;
  int g = (fblk & 7) * 64 + (fblk >> 3);
  int h = g & 63, b = (g >> 6) & 3, ch2 = g >> 8;
  int co0 = ch2 * 128;
  int wm = wid & 1, wn = wid >> 1;
  const int dil[3] = {1, 3, 5};
  f32x4 accd[3][2][4] = {};
  for (int kh = 0; kh < 3; kh++) {
    for (int c = 0; c < 4; c++) {
      __syncthreads();
      const char* wq_base = (const char*)Wq + kh * 3 * 131072 + co0 * 512 + c * 128;
      for (int ch = wid * 1024; ch < 49152; ch += 4096) {
        int o = ch + lane * 16;
        int kw = o >> 14;
        int r = (o >> 7) & 127;
        int col = (o & 127) ^ ((r & 7) << 4);
        gld_lds16(Bs + ch, wq_base + kw * 131072 + r * 512 + col);
      }
      int nst = (kh == 1) ? 1 : 3;     // kh==1: all dilations read row h+5 -> stage once
      for (int di = 0; di < nst; di++) {
        int pr = h + (kh - 1) * dil[di] + 5;             // always in [0,74)
        const char* gsrc = xpad + (size_t)((b * 74 + pr) * 74) * 512 + c * 128;
        char* Ad = As + di * 10240;
        for (int ch = wid * 1024; ch < 9472; ch += 4096) {
          int o = ch + lane * 16;
          if (o < 9472) {
            int r = o >> 7;
            int col = (o & 127) ^ ((r & 7) << 4);
            gld_lds16(Ad + ch, gsrc + r * 512 + col);
          }
        }
      }
      asm volatile("s_waitcnt vmcnt(0)" ::: "memory");
      __syncthreads();
#pragma unroll
      for (int kw = 0; kw < 3; kw++) {
        f16x8 bf[4][2];                 // B doesn't depend on dilation: read once per kw
#pragma unroll
        for (int n = 0; n < 4; n++)
#pragma unroll
          for (int kt = 0; kt < 2; kt++) {
            int rc = wn * 64 + n * 16 + l15;
            bf[n][kt] = *(const f16x8*)(Bs + kw * 16384 + ((rc * 128 + kt * 64 + q4 * 16) ^ ((rc & 7) << 4)));
          }
#pragma unroll
        for (int di = 0; di < 3; di++) {
          int d = dil[di];
          const char* Ad = As + (kh == 1 ? 0 : di) * 10240;
          int dw = (kw - 1) * d + 5;
          f16x8 af[2][2];
#pragma unroll
          for (int m = 0; m < 2; m++)
#pragma unroll
            for (int kt = 0; kt < 2; kt++) {
              int wp = wm * 32 + m * 16 + l15 + dw;      // [0,73]
              af[m][kt] = *(const f16x8*)(Ad + ((wp * 128 + kt * 64 + q4 * 16) ^ ((wp & 7) << 4)));
            }
#pragma unroll
          for (int m = 0; m < 2; m++)
#pragma unroll
            for (int n = 0; n < 4; n++)
#pragma unroll
              for (int kt = 0; kt < 2; kt++)
                accd[di][m][n] = __builtin_amdgcn_mfma_f32_16x16x32_f16(af[m][kt], bf[n][kt], accd[di][m][n], 0, 0, 0);
        }
      }
    }
  }
  const float LOG2E = 1.4426950408889634f;
  const float QSCALE = 0.12751879523176862f;  // log2e / sqrt(128)
#pragma unroll
  for (int n = 0; n < 4; n++) {
    float bias = qb[co0 + wn * 64 + n * 16 + l15];
#pragma unroll
    for (int m = 0; m < 2; m++)
#pragma unroll
      for (int j = 0; j < 4; j++) {
        float s = 0.f;
#pragma unroll
        for (int di = 0; di < 3; di++) {
          float v = accd[di][m][n][j] + bias;
          s += v * v_rcp(1.0f + v_exp2(-v * LOG2E));     // SiLU
        }
        int px = wm * 32 + m * 16 + q4 * 4 + j;
        int dd = wn * 64 + n * 16 + l15;
        int npix = h * 64 + px;
        Q[((size_t)(b * 2 + ch2) * 4096 + npix) * 128 + dd] = f2h(s * QSCALE);
      }
  }
}

// ---------- flash attention, KV-split in 2 halves: 1D grid 512 (XCD-swizzled), 2 blocks/CU ----------
// K staged in LDS (double-buffered); V read DIRECT from global (L2) - halves LDS port traffic.
// P stays in registers (V global layout m-permuted; slot bijection, see k_conv_kv).
// half 0: writes unnormalized O (f32) to out + (m,l) to mlbuf
// half 1: writes normalized O (f16) to o1buf + (m,l) to mlbuf
__global__ __launch_bounds__(256, 2) void k_attn(
    const unsigned short* __restrict__ Q, const unsigned short* __restrict__ K,
    const unsigned short* __restrict__ V, float* __restrict__ out,
    unsigned short* __restrict__ o1buf, float* __restrict__ mlbuf) {
  __shared__ char sm[32768];
  char* K0 = sm;                         // [64m][128d] 16KB each, swz16
  char* K1 = sm + 16384;
  int t = threadIdx.x, lane = t & 63, wid = t >> 6, q4 = lane >> 4, l15 = lane & 15;
  int fblk = blockIdx.x;
  int g = (fblk & 7) * 64 + (fblk >> 3); // XCD swizzle: each XCD gets 2 complete (bh,half) groups
  int nb = g & 31, bh = (g >> 5) & 7, half = g >> 8;
  int b = bh >> 1, hh = bh & 1;
  int n0 = nb * 128;
  const char* Qg = (const char*)(Q + ((size_t)bh * 4096 + n0) * 128);
  const char* Kg = (const char*)(K + (size_t)bh * 4096 * 128) + half * 524288;   // 32 tiles * 16KB
  const char* Vg = (const char*)(V + (size_t)bh * 128 * 4096) + half * 4096;     // 2048 m * 2B
  // Q fragments direct from global (read once; no LDS staging)
  f16x8 qf[2][4];
#pragma unroll
  for (int nt = 0; nt < 2; nt++)
#pragma unroll
    for (int kt = 0; kt < 4; kt++) {
      int rn = wid * 32 + nt * 16 + l15;
      qf[nt][kt] = *(const f16x8*)(Qg + (size_t)rn * 256 + kt * 64 + q4 * 16);
    }
  // stage first K tile of this half
  for (int ch = wid * 1024; ch < 16384; ch += 4096) {
    int o = ch + lane * 16;
    gld_lds16(K0 + ch, Kg + (o ^ (((o >> 8) & 15) << 4)));
  }
  asm volatile("s_waitcnt vmcnt(0)" ::: "memory");
  __syncthreads();
  f32x4 Ofr[8][2] = {};                  // O^T frags: [d-tile][n-tile], col n = l15
  float mrun[2] = {-3e38f, -3e38f};
  float lrun[2] = {0.f, 0.f};
  for (int it = 0; it < 32; it++) {
    char* Kc = (it & 1) ? K1 : K0;
    // V fragments for this tile: direct from global, issued first (latency hides under QK+softmax)
    const char* vrow = Vg + (size_t)it * 128;
    f16x8 vfA[8], vfB[8];
#pragma unroll
    for (int dt = 0; dt < 8; dt++) {
      const char* p = vrow + (size_t)(dt * 16 + l15) * 8192 + q4 * 16;
      vfA[dt] = *(const f16x8*)p;
      vfB[dt] = *(const f16x8*)(p + 64);
    }
    if (it < 31) {                       // prefetch next K tile into other buffer
      char* Kn = (it & 1) ? K0 : K1;
      const char* kg = Kg + (size_t)(it + 1) * 16384;
      for (int ch = wid * 1024; ch < 16384; ch += 4096) {
        int o = ch + lane * 16;
        gld_lds16(Kn + ch, kg + (o ^ (((o >> 8) & 15) << 4)));
      }
    }
    // S^T[m][n] = sum_d K[m][d] Q[n][d]   (swapped operands: softmax state is per-column n = l15)
    f32x4 sT[4][2] = {};
#pragma unroll
    for (int kt = 0; kt < 4; kt++) {
      f16x8 kf[4];
#pragma unroll
      for (int mt = 0; mt < 4; mt++) {
        int rm = mt * 16 + l15;
        kf[mt] = *(const f16x8*)(Kc + ((rm * 256 + kt * 64 + q4 * 16) ^ ((rm & 15) << 4)));
      }
      __builtin_amdgcn_s_setprio(1);
#pragma unroll
      for (int mt = 0; mt < 4; mt++)
#pragma unroll
        for (int nt = 0; nt < 2; nt++)
          sT[mt][nt] = __builtin_amdgcn_mfma_f32_16x16x32_f16(kf[mt], qf[nt][kt], sT[mt][nt], 0, 0, 0);
      __builtin_amdgcn_s_setprio(0);
    }
    // online softmax over m (rows), defer-max rescale (threshold 8); P packed to regs
    unsigned U[2][4][2];
#pragma unroll
    for (int nt = 0; nt < 2; nt++) {
      float mx = sT[0][nt][0];
#pragma unroll
      for (int mt = 0; mt < 4; mt++)
#pragma unroll
        for (int j = 0; j < 4; j++) mx = fmaxf(mx, sT[mt][nt][j]);
      mx = fmaxf(mx, __shfl_xor(mx, 16));
      mx = fmaxf(mx, __shfl_xor(mx, 32));
      float mn = mrun[nt];
      if (!__all(mx - mn <= 8.f)) {      // rare: real max growth -> rescale
        mn = fmaxf(mrun[nt], mx);
        float al = v_exp2(mrun[nt] - mn);
        mrun[nt] = mn;
        lrun[nt] *= al;
#pragma unroll
        for (int dt = 0; dt < 8; dt++) Ofr[dt][nt] *= al;
      }
      float rs = 0.f;
#pragma unroll
      for (int mt = 0; mt < 4; mt++) {
        float p0 = v_exp2(sT[mt][nt][0] - mn);
        float p1 = v_exp2(sT[mt][nt][1] - mn);
        float p2 = v_exp2(sT[mt][nt][2] - mn);
        float p3 = v_exp2(sT[mt][nt][3] - mn);
        rs += (p0 + p1) + (p2 + p3);
        U[nt][mt][0] = pk2h(p0, p1);
        U[nt][mt][1] = pk2h(p2, p3);
      }
      rs += __shfl_xor(rs, 16);
      rs += __shfl_xor(rs, 32);
      lrun[nt] += rs;
    }
    // O^T += V * P.  pf is lane-local: slot (q4,e) <-> m = kt*32 + (e>>2)*16 + q4*4 + (e&3),
    // matching V's permuted storage s = kt*32 + q4*8 + e.
#pragma unroll
    for (int kt = 0; kt < 2; kt++) {
      f16x8 pf[2];
#pragma unroll
      for (int nt = 0; nt < 2; nt++) {
        uint4 fr;
        fr.x = U[nt][2 * kt][0];
        fr.y = U[nt][2 * kt][1];
        fr.z = U[nt][2 * kt + 1][0];
        fr.w = U[nt][2 * kt + 1][1];
        pf[nt] = __builtin_bit_cast(f16x8, fr);
      }
      __builtin_amdgcn_s_setprio(1);
#pragma unroll
      for (int dt = 0; dt < 8; dt++)
#pragma unroll
        for (int nt = 0; nt < 2; nt++)
          Ofr[dt][nt] = __builtin_amdgcn_mfma_f32_16x16x32_f16(kt ? vfB[dt] : vfA[dt], pf[nt], Ofr[dt][nt], 0, 0, 0);
      __builtin_amdgcn_s_setprio(0);
    }
    __syncthreads();
  }
  // write (m,l) per q-column
  if (q4 == 0) {
#pragma unroll
    for (int nt = 0; nt < 2; nt++) {
      int n = n0 + wid * 32 + nt * 16 + l15;
      float2 ml;
      ml.x = mrun[nt];
      ml.y = lrun[nt];
      *(float2*)(mlbuf + ((size_t)(half * 8 + bh) * 4096 + n) * 2) = ml;
    }
  }
  if (half == 0) {
    float* og = out + (size_t)(b * 256 + hh * 128) * 4096 + n0 + wid * 32;
#pragma unroll
    for (int dt = 0; dt < 8; dt++)
#pragma unroll
      for (int nt = 0; nt < 2; nt++)
#pragma unroll
        for (int j = 0; j < 4; j++) {
          int dd = dt * 16 + q4 * 4 + j;
          og[(size_t)dd * 4096 + nt * 16 + l15] = Ofr[dt][nt][j];
        }
  } else {
    float li[2] = {v_rcp(lrun[0]), v_rcp(lrun[1])};
    unsigned short* og = o1buf + (size_t)bh * 128 * 4096 + n0 + wid * 32;
#pragma unroll
    for (int dt = 0; dt < 8; dt++)
#pragma unroll
      for (int nt = 0; nt < 2; nt++)
#pragma unroll
        for (int j = 0; j < 4; j++) {
          int dd = dt * 16 + q4 * 4 + j;
          og[(size_t)dd * 4096 + nt * 16 + l15] = f2h(Ofr[dt][nt][j] * li[nt]);
        }
  }
}

// ---------- combine the two KV halves (in-place on out) ----------
__global__ __launch_bounds__(256) void k_combine(
    float* __restrict__ out, const unsigned short* __restrict__ o1,
    const float* __restrict__ ml) {
  int tid = blockIdx.x * 256 + threadIdx.x;    // bits: [0:11]=n, [12:14]=dg, [15:17]=bh
  int n = tid & 4095, dg = (tid >> 12) & 7, bh = tid >> 15;
  float2 ml0 = *(const float2*)(ml + ((size_t)bh * 4096 + n) * 2);
  float2 ml1 = *(const float2*)(ml + ((size_t)(8 + bh) * 4096 + n) * 2);
  float ms = fmaxf(ml0.x, ml1.x);
  float a0 = v_exp2(ml0.x - ms);
  float w1 = ml1.y * v_exp2(ml1.x - ms);
  float inv = 1.f / (ml0.y * a0 + w1);
  size_t ob = ((size_t)((bh >> 1) * 256 + (bh & 1) * 128 + dg * 16)) * 4096 + n;
  size_t o1b = ((size_t)(bh * 128 + dg * 16)) * 4096 + n;
#pragma unroll 4
  for (int j = 0; j < 16; j++) {
    float v0 = out[ob + (size_t)j * 4096];
    float v1 = h2f(o1[o1b + (size_t)j * 4096]);
    out[ob + (size_t)j * 4096] = (v0 * a0 + v1 * w1) * inv;
  }
}

extern "C" void kernel_launch(void* const* d_in, const int* in_sizes, int n_in,
                              void* d_out, int out_size, void* d_ws, size_t ws_size,
                              hipStream_t stream) {
  (void)in_sizes; (void)n_in; (void)out_size;
  const float* x  = (const float*)d_in[0];
  const float* qw = (const float*)d_in[1];
  const float* qb = (const float*)d_in[2];
  const float* kw = (const float*)d_in[3];
  const float* kb = (const float*)d_in[4];
  const float* vw = (const float*)d_in[5];
  const float* vb = (const float*)d_in[6];
  char* ws = (char*)d_ws;
  if (ws_size < 37822464) return;
  char* xpad = ws;
  unsigned short* Wq = (unsigned short*)(ws + 11214848);
  unsigned short* Wk = (unsigned short*)(ws + 12394496);
  unsigned short* Wv = (unsigned short*)(ws + 12525568);
  unsigned short* Qb = (unsigned short*)(ws + 12656640);
  unsigned short* Kb = (unsigned short*)(ws + 21045248);
  unsigned short* Vb = (unsigned short*)(ws + 29433856);
  unsigned short* O1 = (unsigned short*)ws;            // reuse xpad after convs (8.4MB)
  float* ML = (float*)(ws + 11214848);                 // reuse Wq after convs (512KB)
  hipMemsetAsync(xpad, 0, 11214848, stream);
  k_prep_x<<<dim3(64, 4), dim3(256), 0, stream>>>(x, xpad);
  k_prep_w<<<dim3(256), dim3(256), 0, stream>>>(qw, kw, vw, Wq, Wk, Wv);
  k_conv_kv<<<dim3(128, 2, 2), dim3(256), 0, stream>>>(xpad, Wk, Wv, kb, vb, Kb, Vb);
  k_conv_q<<<dim3(512), dim3(256), 79872, stream>>>(xpad, Wq, qb, Qb);
  k_attn<<<dim3(512), dim3(256), 0, stream>>>(Qb, Kb, Vb, (float*)d_out, O1, ML);
  k_combine<<<dim3(1024), dim3(256), 0, stream>>>((float*)d_out, O1, ML);
}

// Round 7
// 179.656 us; speedup vs baseline: 1.3293x; 1.3293x over previous
//
#include <hip/hip_runtime.h>
#include <cstdint>

typedef __attribute__((ext_vector_type(8))) _Float16 f16x8;
typedef __attribute__((ext_vector_type(4))) float f32x4;

#define DEV static __device__ __forceinline__

DEV void gld_lds16(void* lds_base, const void* gsrc) {
  __builtin_amdgcn_global_load_lds(
      (const __attribute__((address_space(1))) unsigned int*)gsrc,
      (__attribute__((address_space(3))) unsigned int*)lds_base,
      16, 0, 0);
}
DEV unsigned short f2h(float f) {
  _Float16 h = (_Float16)f;
  return __builtin_bit_cast(unsigned short, h);
}
DEV float h2f(unsigned short u) {
  _Float16 h = __builtin_bit_cast(_Float16, u);
  return (float)h;
}
DEV unsigned pk2h(float a, float b) {
  auto h2 = __builtin_amdgcn_cvt_pkrtz(a, b);
  return __builtin_bit_cast(unsigned, h2);
}
DEV float v_exp2(float x) { float r; asm("v_exp_f32 %0, %1" : "=v"(r) : "v"(x)); return r; }
DEV float v_rcp(float x) { float r; asm("v_rcp_f32 %0, %1" : "=v"(r) : "v"(x)); return r; }

// ---------------- geometry ----------------
// B=4, C=256, H=W=64, N=4096, heads=2, hd=128
// ws layout (bytes):
//   Xpad [4][74][74][256] f16 : 0        .. 11214848   (reused as O1 f16 [8][128][4096] during attn)
//   Wq [3][3][256][256] f16   : 11214848 .. 12394496   (reused as ml buf [2][8][4096][2] f32 during attn)
//   Wk [256][256] f16         : 12394496 .. 12525568
//   Wv [256][256] f16         : 12525568 .. 12656640
//   Q  [8][4096][128] f16     : 12656640 .. 21045248   (pre-scaled by log2e/sqrt(128))
//   K  [8][4096][128] f16     : 21045248 .. 29433856
//   V  [8][128][4096] f16     : 29433856 .. 37822464   (m-permuted per 64-block: s=[m5,m3,m2,m4,m1,m0])

// ---------- prep: x (f32 NCHW) -> Xpad (f16, pixel-major, halo 5) ----------
__global__ __launch_bounds__(256) void k_prep_x(const float* __restrict__ x, char* __restrict__ xpad) {
  __shared__ float xs[32 * 257];
  int h = blockIdx.x, b = blockIdx.y, t = threadIdx.x;
  const float* xb = x + (size_t)b * 1048576 + h * 64;
  for (int half = 0; half < 2; half++) {
    int w0 = half * 32;
    for (int kk = 0; kk < 32; kk++) {
      int flat = kk * 256 + t;       // ci*32 + w
      int ci = flat >> 5, w = flat & 31;
      xs[w * 257 + ci] = xb[ci * 4096 + w0 + w];
    }
    __syncthreads();
    for (int g = 0; g < 4; g++) {
      int w = g * 8 + (t >> 5);
      int cg = t & 31;               // 8-ci chunk
      float v0 = xs[w * 257 + cg * 8 + 0], v1 = xs[w * 257 + cg * 8 + 1];
      float v2 = xs[w * 257 + cg * 8 + 2], v3 = xs[w * 257 + cg * 8 + 3];
      float v4 = xs[w * 257 + cg * 8 + 4], v5 = xs[w * 257 + cg * 8 + 5];
      float v6 = xs[w * 257 + cg * 8 + 6], v7 = xs[w * 257 + cg * 8 + 7];
      uint4 pk;
      pk.x = pk2h(v0, v1);
      pk.y = pk2h(v2, v3);
      pk.z = pk2h(v4, v5);
      pk.w = pk2h(v6, v7);
      *(uint4*)(xpad + ((size_t)((b * 74 + h + 5) * 74) + w0 + w + 5) * 512 + cg * 16) = pk;
    }
    __syncthreads();
  }
}

// ---------- prep: weights -> f16 ----------
__global__ __launch_bounds__(256) void k_prep_w(
    const float* __restrict__ qw, const float* __restrict__ kw, const float* __restrict__ vw,
    unsigned short* __restrict__ Wq, unsigned short* __restrict__ Wk, unsigned short* __restrict__ Wv) {
  int gid = blockIdx.x * 256 + threadIdx.x;   // co*256+ci
  const float* q9 = qw + (size_t)gid * 9;
#pragma unroll
  for (int tp = 0; tp < 9; tp++) Wq[tp * 65536 + gid] = f2h(q9[tp]);
  Wk[gid] = f2h(kw[gid]);
  Wv[gid] = f2h(vw[gid]);
}

// ---------- 1x1 convs: K[bh][m][d], V[bh][d][s(m)] ----------
__global__ __launch_bounds__(256, 2) void k_conv_kv(
    const char* __restrict__ xpad, const unsigned short* __restrict__ Wk,
    const unsigned short* __restrict__ Wv, const float* __restrict__ kb,
    const float* __restrict__ vb, unsigned short* __restrict__ K, unsigned short* __restrict__ V) {
  __shared__ char sm[32768];
  char* Xs = sm;
  char* Ws = sm + 16384;
  int t = threadIdx.x, lane = t & 63, wid = t >> 6, q4 = lane >> 4, l15 = lane & 15;
  int px0 = blockIdx.x * 128;
  int b = px0 >> 12, nn = px0 & 4095;
  int h = blockIdx.y;          // co half / head
  int mode = blockIdx.z;       // 0: K (D[px][co]),  1: V (D[co][px])
  int co0 = h * 128;
  const char* Wsrc = (const char*)(mode ? Wv : Wk);
  int wm = wid & 1, wn = wid >> 1;
  f32x4 acc[4][4] = {};
  for (int c = 0; c < 4; c++) {
    __syncthreads();
    for (int ch = wid * 1024; ch < 16384; ch += 4096) {   // X tile [128px][64ci]
      int o = ch + lane * 16;
      int r = o >> 7;
      int n = nn + r, hh = n >> 6, ww2 = n & 63;
      int col = (o & 127) ^ ((r & 7) << 4);
      gld_lds16(Xs + ch, xpad + ((size_t)((b * 74 + hh + 5) * 74) + ww2 + 5) * 512 + c * 128 + col);
    }
    for (int ch = wid * 1024; ch < 16384; ch += 4096) {   // W tile [128co][64ci]
      int o = ch + lane * 16;
      int r = o >> 7;
      int col = (o & 127) ^ ((r & 7) << 4);
      gld_lds16(Ws + ch, Wsrc + (co0 + r) * 512 + c * 128 + col);
    }
    asm volatile("s_waitcnt vmcnt(0)" ::: "memory");
    __syncthreads();
    int xg = mode ? wn : wm;   // X-frag 64-row group
    int wg = mode ? wm : wn;   // W-frag 64-row group
#pragma unroll
    for (int kt = 0; kt < 2; kt++) {
      f16x8 xf[4], wf[4];
#pragma unroll
      for (int i = 0; i < 4; i++) {
        int rx = xg * 64 + i * 16 + l15;
        xf[i] = *(const f16x8*)(Xs + ((rx * 128 + kt * 64 + q4 * 16) ^ ((rx & 7) << 4)));
        int rw = wg * 64 + i * 16 + l15;
        wf[i] = *(const f16x8*)(Ws + ((rw * 128 + kt * 64 + q4 * 16) ^ ((rw & 7) << 4)));
      }
#pragma unroll
      for (int m = 0; m < 4; m++)
#pragma unroll
        for (int n = 0; n < 4; n++)
          acc[m][n] = mode ? __builtin_amdgcn_mfma_f32_16x16x32_f16(wf[m], xf[n], acc[m][n], 0, 0, 0)
                           : __builtin_amdgcn_mfma_f32_16x16x32_f16(xf[m], wf[n], acc[m][n], 0, 0, 0);
    }
  }
  int bh = b * 2 + h;
  if (mode == 0) {
#pragma unroll
    for (int m = 0; m < 4; m++)
#pragma unroll
      for (int n = 0; n < 4; n++) {
        int dd = wn * 64 + n * 16 + l15;
        float bias = kb[co0 + dd];
#pragma unroll
        for (int j = 0; j < 4; j++) {
          int npix = nn + wm * 64 + m * 16 + q4 * 4 + j;
          K[(size_t)(bh * 4096 + npix) * 128 + dd] = f2h(acc[m][n][j] + bias);
        }
      }
  } else {
#pragma unroll
    for (int m = 0; m < 4; m++)
#pragma unroll
      for (int j = 0; j < 4; j++) {
        int cr = wm * 64 + m * 16 + q4 * 4 + j;
        float bias = vb[co0 + cr];
#pragma unroll
        for (int n = 0; n < 4; n++) {
          // m-permuted storage within each 64-block: m_local = n*16 + l15
          // -> s = (n>>1)*32 + (l15>>2)*8 + (n&1)*4 + (l15&3)
          int pc = nn + wn * 64 + (n >> 1) * 32 + (l15 >> 2) * 8 + (n & 1) * 4 + (l15 & 3);
          V[(size_t)(bh * 128 + cr) * 4096 + pc] = f2h(acc[m][n][j] + bias);
        }
      }
  }
}

// ---------- dilated 3x3 conv sum(SiLU) -> Q[bh][n][d] ----------
// 1D grid 512, XCD swizzle: each XCD owns one (b, ch2) pair (X batch + W half L2-resident)
__global__ __launch_bounds__(256, 2) void k_conv_q(
    const char* __restrict__ xpad, const unsigned short* __restrict__ Wq,
    const float* __restrict__ qb, unsigned short* __restrict__ Q) {
  extern __shared__ char sm[];
  char* Bs = sm;               // [3 kw][128 co][64 ci] f16 = 49152
  char* As = sm + 49152;       // 3 x [74 w][64 ci] f16 (pitch 10240)
  int t = threadIdx.x, lane = t & 63, wid = t >> 6, q4 = lane >> 4, l15 = lane & 15;
  int fblk = blockIdx.x;
  int g = (fblk & 7) * 64 + (fblk >> 3);
  int h = g & 63, b = (g >> 6) & 3, ch2 = g >> 8;
  int co0 = ch2 * 128;
  int wm = wid & 1, wn = wid >> 1;
  const int dil[3] = {1, 3, 5};
  f32x4 accd[3][2][4] = {};
  for (int kh = 0; kh < 3; kh++) {
    for (int c = 0; c < 4; c++) {
      __syncthreads();
      const char* wq_base = (const char*)Wq + kh * 3 * 131072 + co0 * 512 + c * 128;
      for (int ch = wid * 1024; ch < 49152; ch += 4096) {
        int o = ch + lane * 16;
        int kw = o >> 14;
        int r = (o >> 7) & 127;
        int col = (o & 127) ^ ((r & 7) << 4);
        gld_lds16(Bs + ch, wq_base + kw * 131072 + r * 512 + col);
      }
      int nst = (kh == 1) ? 1 : 3;     // kh==1: all dilations read row h+5 -> stage once
      for (int di = 0; di < nst; di++) {
        int pr = h + (kh - 1) * dil[di] + 5;             // always in [0,74)
        const char* gsrc = xpad + (size_t)((b * 74 + pr) * 74) * 512 + c * 128;
        char* Ad = As + di * 10240;
        for (int ch = wid * 1024; ch < 9472; ch += 4096) {
          int o = ch + lane * 16;
          if (o < 9472) {
            int r = o >> 7;
            int col = (o & 127) ^ ((r & 7) << 4);
            gld_lds16(Ad + ch, gsrc + r * 512 + col);
          }
        }
      }
      asm volatile("s_waitcnt vmcnt(0)" ::: "memory");
      __syncthreads();
#pragma unroll
      for (int kw = 0; kw < 3; kw++) {
        f16x8 bf[4][2];                 // B doesn't depend on dilation: read once per kw
#pragma unroll
        for (int n = 0; n < 4; n++)
#pragma unroll
          for (int kt = 0; kt < 2; kt++) {
            int rc = wn * 64 + n * 16 + l15;
            bf[n][kt] = *(const f16x8*)(Bs + kw * 16384 + ((rc * 128 + kt * 64 + q4 * 16) ^ ((rc & 7) << 4)));
          }
#pragma unroll
        for (int di = 0; di < 3; di++) {
          int d = dil[di];
          const char* Ad = As + (kh == 1 ? 0 : di) * 10240;
          int dw = (kw - 1) * d + 5;
          f16x8 af[2][2];
#pragma unroll
          for (int m = 0; m < 2; m++)
#pragma unroll
            for (int kt = 0; kt < 2; kt++) {
              int wp = wm * 32 + m * 16 + l15 + dw;      // [0,73]
              af[m][kt] = *(const f16x8*)(Ad + ((wp * 128 + kt * 64 + q4 * 16) ^ ((wp & 7) << 4)));
            }
#pragma unroll
          for (int m = 0; m < 2; m++)
#pragma unroll
            for (int n = 0; n < 4; n++)
#pragma unroll
              for (int kt = 0; kt < 2; kt++)
                accd[di][m][n] = __builtin_amdgcn_mfma_f32_16x16x32_f16(af[m][kt], bf[n][kt], accd[di][m][n], 0, 0, 0);
        }
      }
    }
  }
  const float LOG2E = 1.4426950408889634f;
  const float QSCALE = 0.12751879523176862f;  // log2e / sqrt(128)
#pragma unroll
  for (int n = 0; n < 4; n++) {
    float bias = qb[co0 + wn * 64 + n * 16 + l15];
#pragma unroll
    for (int m = 0; m < 2; m++)
#pragma unroll
      for (int j = 0; j < 4; j++) {
        float s = 0.f;
#pragma unroll
        for (int di = 0; di < 3; di++) {
          float v = accd[di][m][n][j] + bias;
          s += v * v_rcp(1.0f + v_exp2(-v * LOG2E));     // SiLU
        }
        int px = wm * 32 + m * 16 + q4 * 4 + j;
        int dd = wn * 64 + n * 16 + l15;
        int npix = h * 64 + px;
        Q[((size_t)(b * 2 + ch2) * 4096 + npix) * 128 + dd] = f2h(s * QSCALE);
      }
  }
}

// ---------- flash attention, KV-split in 2 halves: 1D grid 512 (XCD-swizzled), 2 blocks/CU ----------
// K and V staged in LDS (double-buffered, gld_lds); P stays in registers
// (V global layout m-permuted; slot bijection, see k_conv_kv).
// half 0: writes unnormalized O (f32) to out + (m,l) to mlbuf
// half 1: writes normalized O (f16) to o1buf + (m,l) to mlbuf
__global__ __launch_bounds__(256, 2) void k_attn(
    const unsigned short* __restrict__ Q, const unsigned short* __restrict__ K,
    const unsigned short* __restrict__ V, float* __restrict__ out,
    unsigned short* __restrict__ o1buf, float* __restrict__ mlbuf) {
  __shared__ char sm[65536];
  char* K0 = sm;                         // [64m][128d] 16KB each, swz16
  char* K1 = sm + 16384;
  char* V0 = sm + 32768;                 // [128d][64s] 16KB each, swz8
  char* V1 = sm + 49152;
  int t = threadIdx.x, lane = t & 63, wid = t >> 6, q4 = lane >> 4, l15 = lane & 15;
  int fblk = blockIdx.x;
  int g = (fblk & 7) * 64 + (fblk >> 3); // XCD swizzle: each XCD gets 2 complete (bh,half) groups
  int nb = g & 31, bh = (g >> 5) & 7, half = g >> 8;
  int b = bh >> 1, hh = bh & 1;
  int n0 = nb * 128;
  const char* Qg = (const char*)(Q + ((size_t)bh * 4096 + n0) * 128);
  const char* Kg = (const char*)(K + (size_t)bh * 4096 * 128) + half * 524288;   // 32 tiles * 16KB
  const char* Vg = (const char*)(V + (size_t)bh * 128 * 4096) + half * 4096;     // 2048 m * 2B
  // Q fragments direct from global (read once; no LDS staging)
  f16x8 qf[2][4];
#pragma unroll
  for (int nt = 0; nt < 2; nt++)
#pragma unroll
    for (int kt = 0; kt < 4; kt++) {
      int rn = wid * 32 + nt * 16 + l15;
      qf[nt][kt] = *(const f16x8*)(Qg + (size_t)rn * 256 + kt * 64 + q4 * 16);
    }
  // stage first K/V tile of this half
  for (int ch = wid * 1024; ch < 16384; ch += 4096) {
    int o = ch + lane * 16;
    gld_lds16(K0 + ch, Kg + (o ^ (((o >> 8) & 15) << 4)));
  }
  for (int ch = wid * 1024; ch < 16384; ch += 4096) {
    int o = ch + lane * 16;
    int dd = o >> 7;
    int col = (o & 127) ^ ((dd & 7) << 4);
    gld_lds16(V0 + ch, Vg + dd * 8192 + col);
  }
  asm volatile("s_waitcnt vmcnt(0)" ::: "memory");
  __syncthreads();
  f32x4 Ofr[8][2] = {};                  // O^T frags: [d-tile][n-tile], col n = l15
  float mrun[2] = {-3e38f, -3e38f};
  float lrun[2] = {0.f, 0.f};
  for (int it = 0; it < 32; it++) {
    char* Kc = (it & 1) ? K1 : K0;
    char* Vc = (it & 1) ? V1 : V0;
    if (it < 31) {                       // prefetch next tile into other buffer
      char* Kn = (it & 1) ? K0 : K1;
      char* Vn = (it & 1) ? V0 : V1;
      const char* kg = Kg + (size_t)(it + 1) * 16384;
      for (int ch = wid * 1024; ch < 16384; ch += 4096) {
        int o = ch + lane * 16;
        gld_lds16(Kn + ch, kg + (o ^ (((o >> 8) & 15) << 4)));
      }
      const char* vg = Vg + (it + 1) * 128;
      for (int ch = wid * 1024; ch < 16384; ch += 4096) {
        int o = ch + lane * 16;
        int dd = o >> 7;
        int col = (o & 127) ^ ((dd & 7) << 4);
        gld_lds16(Vn + ch, vg + dd * 8192 + col);
      }
    }
    // S^T[m][n] = sum_d K[m][d] Q[n][d]   (swapped operands: softmax state is per-column n = l15)
    f32x4 sT[4][2] = {};
#pragma unroll
    for (int kt = 0; kt < 4; kt++) {
      f16x8 kf[4];
#pragma unroll
      for (int mt = 0; mt < 4; mt++) {
        int rm = mt * 16 + l15;
        kf[mt] = *(const f16x8*)(Kc + ((rm * 256 + kt * 64 + q4 * 16) ^ ((rm & 15) << 4)));
      }
      __builtin_amdgcn_s_setprio(1);
#pragma unroll
      for (int mt = 0; mt < 4; mt++)
#pragma unroll
        for (int nt = 0; nt < 2; nt++)
          sT[mt][nt] = __builtin_amdgcn_mfma_f32_16x16x32_f16(kf[mt], qf[nt][kt], sT[mt][nt], 0, 0, 0);
      __builtin_amdgcn_s_setprio(0);
    }
    // online softmax over m (rows), defer-max rescale (threshold 8); P packed to regs
    unsigned U[2][4][2];
#pragma unroll
    for (int nt = 0; nt < 2; nt++) {
      float mx = sT[0][nt][0];
#pragma unroll
      for (int mt = 0; mt < 4; mt++)
#pragma unroll
        for (int j = 0; j < 4; j++) mx = fmaxf(mx, sT[mt][nt][j]);
      mx = fmaxf(mx, __shfl_xor(mx, 16));
      mx = fmaxf(mx, __shfl_xor(mx, 32));
      float mn = mrun[nt];
      if (!__all(mx - mn <= 8.f)) {      // rare: real max growth -> rescale
        mn = fmaxf(mrun[nt], mx);
        float al = v_exp2(mrun[nt] - mn);
        mrun[nt] = mn;
        lrun[nt] *= al;
#pragma unroll
        for (int dt = 0; dt < 8; dt++) Ofr[dt][nt] *= al;
      }
      float rs = 0.f;
#pragma unroll
      for (int mt = 0; mt < 4; mt++) {
        float p0 = v_exp2(sT[mt][nt][0] - mn);
        float p1 = v_exp2(sT[mt][nt][1] - mn);
        float p2 = v_exp2(sT[mt][nt][2] - mn);
        float p3 = v_exp2(sT[mt][nt][3] - mn);
        rs += (p0 + p1) + (p2 + p3);
        U[nt][mt][0] = pk2h(p0, p1);
        U[nt][mt][1] = pk2h(p2, p3);
      }
      rs += __shfl_xor(rs, 16);
      rs += __shfl_xor(rs, 32);
      lrun[nt] += rs;
    }
    // O^T += V * P.  pf is lane-local: slot (q4,e) <-> m = kt*32 + (e>>2)*16 + q4*4 + (e&3),
    // matching V's permuted storage s = kt*32 + q4*8 + e.
#pragma unroll
    for (int kt = 0; kt < 2; kt++) {
      f16x8 pf[2];
#pragma unroll
      for (int nt = 0; nt < 2; nt++) {
        uint4 fr;
        fr.x = U[nt][2 * kt][0];
        fr.y = U[nt][2 * kt][1];
        fr.z = U[nt][2 * kt + 1][0];
        fr.w = U[nt][2 * kt + 1][1];
        pf[nt] = __builtin_bit_cast(f16x8, fr);
      }
      f16x8 vf[8];
#pragma unroll
      for (int dt = 0; dt < 8; dt++) {
        int rd = dt * 16 + l15;
        vf[dt] = *(const f16x8*)(Vc + ((rd * 128 + kt * 64 + q4 * 16) ^ ((rd & 7) << 4)));
      }
      __builtin_amdgcn_s_setprio(1);
#pragma unroll
      for (int dt = 0; dt < 8; dt++)
#pragma unroll
        for (int nt = 0; nt < 2; nt++)
          Ofr[dt][nt] = __builtin_amdgcn_mfma_f32_16x16x32_f16(vf[dt], pf[nt], Ofr[dt][nt], 0, 0, 0);
      __builtin_amdgcn_s_setprio(0);
    }
    __syncthreads();
  }
  // write (m,l) per q-column
  if (q4 == 0) {
#pragma unroll
    for (int nt = 0; nt < 2; nt++) {
      int n = n0 + wid * 32 + nt * 16 + l15;
      float2 ml;
      ml.x = mrun[nt];
      ml.y = lrun[nt];
      *(float2*)(mlbuf + ((size_t)(half * 8 + bh) * 4096 + n) * 2) = ml;
    }
  }
  if (half == 0) {
    float* og = out + (size_t)(b * 256 + hh * 128) * 4096 + n0 + wid * 32;
#pragma unroll
    for (int dt = 0; dt < 8; dt++)
#pragma unroll
      for (int nt = 0; nt < 2; nt++)
#pragma unroll
        for (int j = 0; j < 4; j++) {
          int dd = dt * 16 + q4 * 4 + j;
          og[(size_t)dd * 4096 + nt * 16 + l15] = Ofr[dt][nt][j];
        }
  } else {
    float li[2] = {v_rcp(lrun[0]), v_rcp(lrun[1])};
    unsigned short* og = o1buf + (size_t)bh * 128 * 4096 + n0 + wid * 32;
#pragma unroll
    for (int dt = 0; dt < 8; dt++)
#pragma unroll
      for (int nt = 0; nt < 2; nt++)
#pragma unroll
        for (int j = 0; j < 4; j++) {
          int dd = dt * 16 + q4 * 4 + j;
          og[(size_t)dd * 4096 + nt * 16 + l15] = f2h(Ofr[dt][nt][j] * li[nt]);
        }
  }
}

// ---------- combine the two KV halves (in-place on out) ----------
__global__ __launch_bounds__(256) void k_combine(
    float* __restrict__ out, const unsigned short* __restrict__ o1,
    const float* __restrict__ ml) {
  int tid = blockIdx.x * 256 + threadIdx.x;    // bits: [0:11]=n, [12:14]=dg, [15:17]=bh
  int n = tid & 4095, dg = (tid >> 12) & 7, bh = tid >> 15;
  float2 ml0 = *(const float2*)(ml + ((size_t)bh * 4096 + n) * 2);
  float2 ml1 = *(const float2*)(ml + ((size_t)(8 + bh) * 4096 + n) * 2);
  float ms = fmaxf(ml0.x, ml1.x);
  float a0 = v_exp2(ml0.x - ms);
  float w1 = ml1.y * v_exp2(ml1.x - ms);
  float inv = 1.f / (ml0.y * a0 + w1);
  size_t ob = ((size_t)((bh >> 1) * 256 + (bh & 1) * 128 + dg * 16)) * 4096 + n;
  size_t o1b = ((size_t)(bh * 128 + dg * 16)) * 4096 + n;
#pragma unroll 4
  for (int j = 0; j < 16; j++) {
    float v0 = out[ob + (size_t)j * 4096];
    float v1 = h2f(o1[o1b + (size_t)j * 4096]);
    out[ob + (size_t)j * 4096] = (v0 * a0 + v1 * w1) * inv;
  }
}

extern "C" void kernel_launch(void* const* d_in, const int* in_sizes, int n_in,
                              void* d_out, int out_size, void* d_ws, size_t ws_size,
                              hipStream_t stream) {
  (void)in_sizes; (void)n_in; (void)out_size;
  const float* x  = (const float*)d_in[0];
  const float* qw = (const float*)d_in[1];
  const float* qb = (const float*)d_in[2];
  const float* kw = (const float*)d_in[3];
  const float* kb = (const float*)d_in[4];
  const float* vw = (const float*)d_in[5];
  const float* vb = (const float*)d_in[6];
  char* ws = (char*)d_ws;
  if (ws_size < 37822464) return;
  char* xpad = ws;
  unsigned short* Wq = (unsigned short*)(ws + 11214848);
  unsigned short* Wk = (unsigned short*)(ws + 12394496);
  unsigned short* Wv = (unsigned short*)(ws + 12525568);
  unsigned short* Qb = (unsigned short*)(ws + 12656640);
  unsigned short* Kb = (unsigned short*)(ws + 21045248);
  unsigned short* Vb = (unsigned short*)(ws + 29433856);
  unsigned short* O1 = (unsigned short*)ws;            // reuse xpad after convs (8.4MB)
  float* ML = (float*)(ws + 11214848);                 // reuse Wq after convs (512KB)
  hipMemsetAsync(xpad, 0, 11214848, stream);
  k_prep_x<<<dim3(64, 4), dim3(256), 0, stream>>>(x, xpad);
  k_prep_w<<<dim3(256), dim3(256), 0, stream>>>(qw, kw, vw, Wq, Wk, Wv);
  k_conv_kv<<<dim3(128, 2, 2), dim3(256), 0, stream>>>(xpad, Wk, Wv, kb, vb, Kb, Vb);
  k_conv_q<<<dim3(512), dim3(256), 79872, stream>>>(xpad, Wq, qb, Qb);
  k_attn<<<dim3(512), dim3(256), 0, stream>>>(Qb, Kb, Vb, (float*)d_out, O1, ML);
  k_combine<<<dim3(1024), dim3(256), 0, stream>>>((float*)d_out, O1, ML);
}

// Round 10
// 179.210 us; speedup vs baseline: 1.3327x; 1.0025x over previous
//
#include <hip/hip_runtime.h>
#include <cstdint>

typedef __attribute__((ext_vector_type(8))) _Float16 f16x8;
typedef __attribute__((ext_vector_type(4))) float f32x4;

#define DEV static __device__ __forceinline__

DEV void gld_lds16(void* lds_base, const void* gsrc) {
  __builtin_amdgcn_global_load_lds(
      (const __attribute__((address_space(1))) unsigned int*)gsrc,
      (__attribute__((address_space(3))) unsigned int*)lds_base,
      16, 0, 0);
}
DEV unsigned short f2h(float f) {
  _Float16 h = (_Float16)f;
  return __builtin_bit_cast(unsigned short, h);
}
DEV float h2f(unsigned short u) {
  _Float16 h = __builtin_bit_cast(_Float16, u);
  return (float)h;
}
DEV unsigned pk2h(float a, float b) {
  auto h2 = __builtin_amdgcn_cvt_pkrtz(a, b);
  return __builtin_bit_cast(unsigned, h2);
}
DEV float v_exp2(float x) { float r; asm("v_exp_f32 %0, %1" : "=v"(r) : "v"(x)); return r; }
DEV float v_rcp(float x) { float r; asm("v_rcp_f32 %0, %1" : "=v"(r) : "v"(x)); return r; }

// ---------------- geometry ----------------
// B=4, C=256, H=W=64, N=4096, heads=2, hd=128
// ws layout (bytes):
//   Xpad [4][74][74][256] f16 : 0        .. 11214848   (reused as O1 f16 [8][128][4096] during attn)
//   Wq [3][3][256][256] f16   : 11214848 .. 12394496   (reused as ml buf [2][8][4096][2] f32 during attn)
//   Wk [256][256] f16         : 12394496 .. 12525568
//   Wv [256][256] f16         : 12525568 .. 12656640
//   Q  [8][4096][128] f16     : 12656640 .. 21045248   (pre-scaled by log2e/sqrt(128))
//   K  [8][4096][128] f16     : 21045248 .. 29433856
//   V  [8][128][4096] f16     : 29433856 .. 37822464   (m-permuted per 64-block: s=[m5,m3,m2,m4,m1,m0])

// ---------- prep: x (f32 NCHW) -> Xpad (f16, pixel-major, halo 5) ----------
__global__ __launch_bounds__(256) void k_prep_x(const float* __restrict__ x, char* __restrict__ xpad) {
  __shared__ float xs[32 * 257];
  int h = blockIdx.x, b = blockIdx.y, t = threadIdx.x;
  const float* xb = x + (size_t)b * 1048576 + h * 64;
  for (int half = 0; half < 2; half++) {
    int w0 = half * 32;
    for (int kk = 0; kk < 32; kk++) {
      int flat = kk * 256 + t;       // ci*32 + w
      int ci = flat >> 5, w = flat & 31;
      xs[w * 257 + ci] = xb[ci * 4096 + w0 + w];
    }
    __syncthreads();
    for (int g = 0; g < 4; g++) {
      int w = g * 8 + (t >> 5);
      int cg = t & 31;               // 8-ci chunk
      float v0 = xs[w * 257 + cg * 8 + 0], v1 = xs[w * 257 + cg * 8 + 1];
      float v2 = xs[w * 257 + cg * 8 + 2], v3 = xs[w * 257 + cg * 8 + 3];
      float v4 = xs[w * 257 + cg * 8 + 4], v5 = xs[w * 257 + cg * 8 + 5];
      float v6 = xs[w * 257 + cg * 8 + 6], v7 = xs[w * 257 + cg * 8 + 7];
      uint4 pk;
      pk.x = pk2h(v0, v1);
      pk.y = pk2h(v2, v3);
      pk.z = pk2h(v4, v5);
      pk.w = pk2h(v6, v7);
      *(uint4*)(xpad + ((size_t)((b * 74 + h + 5) * 74) + w0 + w + 5) * 512 + cg * 16) = pk;
    }
    __syncthreads();
  }
}

// ---------- prep: weights -> f16 ----------
__global__ __launch_bounds__(256) void k_prep_w(
    const float* __restrict__ qw, const float* __restrict__ kw, const float* __restrict__ vw,
    unsigned short* __restrict__ Wq, unsigned short* __restrict__ Wk, unsigned short* __restrict__ Wv) {
  int gid = blockIdx.x * 256 + threadIdx.x;   // co*256+ci
  const float* q9 = qw + (size_t)gid * 9;
#pragma unroll
  for (int tp = 0; tp < 9; tp++) Wq[tp * 65536 + gid] = f2h(q9[tp]);
  Wk[gid] = f2h(kw[gid]);
  Wv[gid] = f2h(vw[gid]);
}

// ---------- 1x1 convs: K[bh][m][d], V[bh][d][s(m)] ----------
__global__ __launch_bounds__(256, 2) void k_conv_kv(
    const char* __restrict__ xpad, const unsigned short* __restrict__ Wk,
    const unsigned short* __restrict__ Wv, const float* __restrict__ kb,
    const float* __restrict__ vb, unsigned short* __restrict__ K, unsigned short* __restrict__ V) {
  __shared__ char sm[32768];
  char* Xs = sm;
  char* Ws = sm + 16384;
  int t = threadIdx.x, lane = t & 63, wid = t >> 6, q4 = lane >> 4, l15 = lane & 15;
  int px0 = blockIdx.x * 128;
  int b = px0 >> 12, nn = px0 & 4095;
  int h = blockIdx.y;          // co half / head
  int mode = blockIdx.z;       // 0: K (D[px][co]),  1: V (D[co][px])
  int co0 = h * 128;
  const char* Wsrc = (const char*)(mode ? Wv : Wk);
  int wm = wid & 1, wn = wid >> 1;
  f32x4 acc[4][4] = {};
  for (int c = 0; c < 4; c++) {
    __syncthreads();
    for (int ch = wid * 1024; ch < 16384; ch += 4096) {   // X tile [128px][64ci]
      int o = ch + lane * 16;
      int r = o >> 7;
      int n = nn + r, hh = n >> 6, ww2 = n & 63;
      int col = (o & 127) ^ ((r & 7) << 4);
      gld_lds16(Xs + ch, xpad + ((size_t)((b * 74 + hh + 5) * 74) + ww2 + 5) * 512 + c * 128 + col);
    }
    for (int ch = wid * 1024; ch < 16384; ch += 4096) {   // W tile [128co][64ci]
      int o = ch + lane * 16;
      int r = o >> 7;
      int col = (o & 127) ^ ((r & 7) << 4);
      gld_lds16(Ws + ch, Wsrc + (co0 + r) * 512 + c * 128 + col);
    }
    asm volatile("s_waitcnt vmcnt(0)" ::: "memory");
    __syncthreads();
    int xg = mode ? wn : wm;   // X-frag 64-row group
    int wg = mode ? wm : wn;   // W-frag 64-row group
#pragma unroll
    for (int kt = 0; kt < 2; kt++) {
      f16x8 xf[4], wf[4];
#pragma unroll
      for (int i = 0; i < 4; i++) {
        int rx = xg * 64 + i * 16 + l15;
        xf[i] = *(const f16x8*)(Xs + ((rx * 128 + kt * 64 + q4 * 16) ^ ((rx & 7) << 4)));
        int rw = wg * 64 + i * 16 + l15;
        wf[i] = *(const f16x8*)(Ws + ((rw * 128 + kt * 64 + q4 * 16) ^ ((rw & 7) << 4)));
      }
#pragma unroll
      for (int m = 0; m < 4; m++)
#pragma unroll
        for (int n = 0; n < 4; n++)
          acc[m][n] = mode ? __builtin_amdgcn_mfma_f32_16x16x32_f16(wf[m], xf[n], acc[m][n], 0, 0, 0)
                           : __builtin_amdgcn_mfma_f32_16x16x32_f16(xf[m], wf[n], acc[m][n], 0, 0, 0);
    }
  }
  int bh = b * 2 + h;
  if (mode == 0) {
#pragma unroll
    for (int m = 0; m < 4; m++)
#pragma unroll
      for (int n = 0; n < 4; n++) {
        int dd = wn * 64 + n * 16 + l15;
        float bias = kb[co0 + dd];
#pragma unroll
        for (int j = 0; j < 4; j++) {
          int npix = nn + wm * 64 + m * 16 + q4 * 4 + j;
          K[(size_t)(bh * 4096 + npix) * 128 + dd] = f2h(acc[m][n][j] + bias);
        }
      }
  } else {
#pragma unroll
    for (int m = 0; m < 4; m++)
#pragma unroll
      for (int j = 0; j < 4; j++) {
        int cr = wm * 64 + m * 16 + q4 * 4 + j;
        float bias = vb[co0 + cr];
#pragma unroll
        for (int n = 0; n < 4; n++) {
          // m-permuted storage within each 64-block: m_local = n*16 + l15
          // -> s = (n>>1)*32 + (l15>>2)*8 + (n&1)*4 + (l15&3)
          int pc = nn + wn * 64 + (n >> 1) * 32 + (l15 >> 2) * 8 + (n & 1) * 4 + (l15 & 3);
          V[(size_t)(bh * 128 + cr) * 4096 + pc] = f2h(acc[m][n][j] + bias);
        }
      }
  }
}

// ---------- dilated 3x3 conv sum(SiLU) -> Q[bh][n][d] ----------
// 512-thread blocks (8 waves), 128 px (2 h-rows) per block, grid 256 (XCD-swizzled).
// Bs double-buffered at kw granularity (16KB units); explicit vmcnt(0) before each
// trailing barrier so prefetch drain doesn't rely on compiler barrier semantics.
// As ([6 rows][74w][64ci]) single-buffered, re-staged per (kh,c).
__global__ __launch_bounds__(512, 2) void k_conv_q(
    const char* __restrict__ xpad, const unsigned short* __restrict__ Wq,
    const float* __restrict__ qb, unsigned short* __restrict__ Q) {
  extern __shared__ char sm[];                 // 2*16384 + 6*9472 = 89600
  char* As = sm + 32768;
  int t = threadIdx.x, lane = t & 63, wid = t >> 6, q4 = lane >> 4, l15 = lane & 15;
  int fblk = blockIdx.x;
  int g = (fblk & 7) * 32 + (fblk >> 3);       // XCD x owns one (b,ch2) combo
  int h2 = g & 31, b = (g >> 5) & 3, ch2 = g >> 7;
  int h0 = h2 * 2;
  int co0 = ch2 * 128;
  int wn = wid & 1, wq = wid >> 1;
  int hr = wq >> 1, wloc = wq & 1;
  const int dil[3] = {1, 3, 5};
  const char* WqB = (const char*)Wq;
  f32x4 accd[3][2][4] = {};

#define STAGE_B(dstbuf, kh_, c_, kw_)                                             \
  {                                                                               \
    const char* src_ = WqB + (size_t)((kh_)*3 + (kw_)) * 131072 + co0 * 512 + (c_)*128; \
    char* dst_ = (dstbuf);                                                        \
    for (int ch = wid * 1024; ch < 16384; ch += 8192) {                           \
      int o = ch + lane * 16;                                                     \
      int r = o >> 7;                                                             \
      int col = (o & 127) ^ ((r & 7) << 4);                                       \
      gld_lds16(dst_ + ch, src_ + r * 512 + col);                                 \
    }                                                                             \
  }

#define STAGE_A_ROW(slot_, pr_, c_)                                               \
  {                                                                               \
    const char* src_ = xpad + ((size_t)(b * 74 + (pr_)) * 74) * 512 + (c_)*128;   \
    char* dst_ = As + (slot_)*9472;                                               \
    for (int ch = wid * 1024; ch < 9472; ch += 8192) {                            \
      int o = ch + lane * 16;                                                     \
      if (o < 9472) {                                                             \
        int r = o >> 7;                                                           \
        int col = (o & 127) ^ ((r & 7) << 4);                                     \
        gld_lds16(dst_ + ch, src_ + r * 512 + col);                               \
      }                                                                           \
    }                                                                             \
  }

#define STAGE_A(kh_, c_)                                                          \
  {                                                                               \
    if ((kh_) == 1) {                                                             \
      for (int s = 0; s < 2; s++) STAGE_A_ROW(s, h0 + s + 5, c_);                 \
    } else {                                                                      \
      for (int di = 0; di < 3; di++)                                              \
        for (int s = 0; s < 2; s++)                                               \
          STAGE_A_ROW(di * 2 + s, h0 + s + ((kh_)-1) * dil[di] + 5, c_);          \
    }                                                                             \
  }

  // prologue
  STAGE_A(0, 0);
  STAGE_B(sm, 0, 0, 0);
  asm volatile("s_waitcnt vmcnt(0)" ::: "memory");
  __syncthreads();

  int cur = 0;
  for (int kh = 0; kh < 3; kh++) {
    for (int c = 0; c < 4; c++) {
      for (int kw = 0; kw < 3; kw++) {
        // prefetch next unit's weights (fully hidden under this unit's compute)
        int kwn = kw + 1, cn = c, khn = kh;
        if (kwn == 3) { kwn = 0; cn = c + 1; if (cn == 4) { cn = 0; khn = kh + 1; } }
        char* Bnext = cur ? sm : sm + 16384;
        if (khn < 3) STAGE_B(Bnext, khn, cn, kwn);
        // compute unit (kh, c, kw)
        const char* Bc = cur ? sm + 16384 : sm;
        f16x8 bf[4][2];
#pragma unroll
        for (int n = 0; n < 4; n++)
#pragma unroll
          for (int kt = 0; kt < 2; kt++) {
            int rc = wn * 64 + n * 16 + l15;
            bf[n][kt] = *(const f16x8*)(Bc + ((rc * 128 + kt * 64 + q4 * 16) ^ ((rc & 7) << 4)));
          }
#pragma unroll
        for (int di = 0; di < 3; di++) {
          int dw = (kw - 1) * dil[di] + 5;
          const char* Ad = As + (kh == 1 ? hr : di * 2 + hr) * 9472;
          f16x8 af[2][2];
#pragma unroll
          for (int m = 0; m < 2; m++)
#pragma unroll
            for (int kt = 0; kt < 2; kt++) {
              int wp = wloc * 32 + m * 16 + l15 + dw;    // [0,73]
              af[m][kt] = *(const f16x8*)(Ad + ((wp * 128 + kt * 64 + q4 * 16) ^ ((wp & 7) << 4)));
            }
          __builtin_amdgcn_s_setprio(1);
#pragma unroll
          for (int m = 0; m < 2; m++)
#pragma unroll
            for (int n = 0; n < 4; n++)
#pragma unroll
              for (int kt = 0; kt < 2; kt++)
                accd[di][m][n] = __builtin_amdgcn_mfma_f32_16x16x32_f16(af[m][kt], bf[n][kt], accd[di][m][n], 0, 0, 0);
          __builtin_amdgcn_s_setprio(0);
        }
        asm volatile("s_waitcnt vmcnt(0)" ::: "memory");  // drain B prefetch explicitly
        __syncthreads();
        cur ^= 1;
      }
      // re-stage As for next (kh,c)
      int cn2 = c + 1, khn2 = kh;
      if (cn2 == 4) { cn2 = 0; khn2 = kh + 1; }
      if (khn2 < 3) {
        STAGE_A(khn2, cn2);
        asm volatile("s_waitcnt vmcnt(0)" ::: "memory");
        __syncthreads();
      }
    }
  }
#undef STAGE_A
#undef STAGE_A_ROW
#undef STAGE_B
  const float LOG2E = 1.4426950408889634f;
  const float QSCALE = 0.12751879523176862f;  // log2e / sqrt(128)
#pragma unroll
  for (int n = 0; n < 4; n++) {
    float bias = qb[co0 + wn * 64 + n * 16 + l15];
#pragma unroll
    for (int m = 0; m < 2; m++)
#pragma unroll
      for (int j = 0; j < 4; j++) {
        float s = 0.f;
#pragma unroll
        for (int di = 0; di < 3; di++) {
          float v = accd[di][m][n][j] + bias;
          s += v * v_rcp(1.0f + v_exp2(-v * LOG2E));     // SiLU
        }
        int w = wloc * 32 + m * 16 + q4 * 4 + j;
        int npix = (h0 + hr) * 64 + w;
        int dd = wn * 64 + n * 16 + l15;
        Q[((size_t)(b * 2 + ch2) * 4096 + npix) * 128 + dd] = f2h(s * QSCALE);
      }
  }
}

// ---------- flash attention, KV-split in 2 halves: 1D grid 512 (XCD-swizzled), 2 blocks/CU ----------
// R7-exact inner loop (proven): K and V staged in LDS (double-buffered); P in registers
// via V m-permutation (slot bijection); shfl_xor reductions.
// half 0: writes unnormalized O (f32) to out + (m,l) to mlbuf
// half 1: writes normalized O (f16) to o1buf + (m,l) to mlbuf
__global__ __launch_bounds__(256, 2) void k_attn(
    const unsigned short* __restrict__ Q, const unsigned short* __restrict__ K,
    const unsigned short* __restrict__ V, float* __restrict__ out,
    unsigned short* __restrict__ o1buf, float* __restrict__ mlbuf) {
  __shared__ char sm[65536];
  char* K0 = sm;                         // [64m][128d] 16KB each, swz16
  char* K1 = sm + 16384;
  char* V0 = sm + 32768;                 // [128d][64s] 16KB each, swz8
  char* V1 = sm + 49152;
  int t = threadIdx.x, lane = t & 63, wid = t >> 6, q4 = lane >> 4, l15 = lane & 15;
  int fblk = blockIdx.x;
  int g = (fblk & 7) * 64 + (fblk >> 3); // XCD swizzle: each XCD gets 2 complete (bh,half) groups
  int nb = g & 31, bh = (g >> 5) & 7, half = g >> 8;
  int b = bh >> 1, hh = bh & 1;
  int n0 = nb * 128;
  const char* Qg = (const char*)(Q + ((size_t)bh * 4096 + n0) * 128);
  const char* Kg = (const char*)(K + (size_t)bh * 4096 * 128) + half * 524288;   // 32 tiles * 16KB
  const char* Vg = (const char*)(V + (size_t)bh * 128 * 4096) + half * 4096;     // 2048 m * 2B
  // Q fragments direct from global (read once; no LDS staging)
  f16x8 qf[2][4];
#pragma unroll
  for (int nt = 0; nt < 2; nt++)
#pragma unroll
    for (int kt = 0; kt < 4; kt++) {
      int rn = wid * 32 + nt * 16 + l15;
      qf[nt][kt] = *(const f16x8*)(Qg + (size_t)rn * 256 + kt * 64 + q4 * 16);
    }
  // stage first K/V tile of this half
  for (int ch = wid * 1024; ch < 16384; ch += 4096) {
    int o = ch + lane * 16;
    gld_lds16(K0 + ch, Kg + (o ^ (((o >> 8) & 15) << 4)));
  }
  for (int ch = wid * 1024; ch < 16384; ch += 4096) {
    int o = ch + lane * 16;
    int dd = o >> 7;
    int col = (o & 127) ^ ((dd & 7) << 4);
    gld_lds16(V0 + ch, Vg + dd * 8192 + col);
  }
  asm volatile("s_waitcnt vmcnt(0)" ::: "memory");
  __syncthreads();
  f32x4 Ofr[8][2] = {};                  // O^T frags: [d-tile][n-tile], col n = l15
  float mrun[2] = {-3e38f, -3e38f};
  float lrun[2] = {0.f, 0.f};
  for (int it = 0; it < 32; it++) {
    char* Kc = (it & 1) ? K1 : K0;
    char* Vc = (it & 1) ? V1 : V0;
    if (it < 31) {                       // prefetch next tile into other buffer
      char* Kn = (it & 1) ? K0 : K1;
      char* Vn = (it & 1) ? V0 : V1;
      const char* kg = Kg + (size_t)(it + 1) * 16384;
      for (int ch = wid * 1024; ch < 16384; ch += 4096) {
        int o = ch + lane * 16;
        gld_lds16(Kn + ch, kg + (o ^ (((o >> 8) & 15) << 4)));
      }
      const char* vg = Vg + (it + 1) * 128;
      for (int ch = wid * 1024; ch < 16384; ch += 4096) {
        int o = ch + lane * 16;
        int dd = o >> 7;
        int col = (o & 127) ^ ((dd & 7) << 4);
        gld_lds16(Vn + ch, vg + dd * 8192 + col);
      }
    }
    // S^T[m][n] = sum_d K[m][d] Q[n][d]   (swapped operands: softmax state is per-column n = l15)
    f32x4 sT[4][2] = {};
#pragma unroll
    for (int kt = 0; kt < 4; kt++) {
      f16x8 kf[4];
#pragma unroll
      for (int mt = 0; mt < 4; mt++) {
        int rm = mt * 16 + l15;
        kf[mt] = *(const f16x8*)(Kc + ((rm * 256 + kt * 64 + q4 * 16) ^ ((rm & 15) << 4)));
      }
      __builtin_amdgcn_s_setprio(1);
#pragma unroll
      for (int mt = 0; mt < 4; mt++)
#pragma unroll
        for (int nt = 0; nt < 2; nt++)
          sT[mt][nt] = __builtin_amdgcn_mfma_f32_16x16x32_f16(kf[mt], qf[nt][kt], sT[mt][nt], 0, 0, 0);
      __builtin_amdgcn_s_setprio(0);
    }
    // online softmax over m (rows), defer-max rescale (threshold 8); P packed to regs
    unsigned U[2][4][2];
#pragma unroll
    for (int nt = 0; nt < 2; nt++) {
      float mx = sT[0][nt][0];
#pragma unroll
      for (int mt = 0; mt < 4; mt++)
#pragma unroll
        for (int j = 0; j < 4; j++) mx = fmaxf(mx, sT[mt][nt][j]);
      mx = fmaxf(mx, __shfl_xor(mx, 16));
      mx = fmaxf(mx, __shfl_xor(mx, 32));
      float mn = mrun[nt];
      if (!__all(mx - mn <= 8.f)) {      // rare: real max growth -> rescale
        mn = fmaxf(mrun[nt], mx);
        float al = v_exp2(mrun[nt] - mn);
        mrun[nt] = mn;
        lrun[nt] *= al;
#pragma unroll
        for (int dt = 0; dt < 8; dt++) Ofr[dt][nt] *= al;
      }
      float rs = 0.f;
#pragma unroll
      for (int mt = 0; mt < 4; mt++) {
        float p0 = v_exp2(sT[mt][nt][0] - mn);
        float p1 = v_exp2(sT[mt][nt][1] - mn);
        float p2 = v_exp2(sT[mt][nt][2] - mn);
        float p3 = v_exp2(sT[mt][nt][3] - mn);
        rs += (p0 + p1) + (p2 + p3);
        U[nt][mt][0] = pk2h(p0, p1);
        U[nt][mt][1] = pk2h(p2, p3);
      }
      rs += __shfl_xor(rs, 16);
      rs += __shfl_xor(rs, 32);
      lrun[nt] += rs;
    }
    // O^T += V * P.  pf is lane-local: slot (q4,e) <-> m = kt*32 + (e>>2)*16 + q4*4 + (e&3),
    // matching V's permuted storage s = kt*32 + q4*8 + e.
#pragma unroll
    for (int kt = 0; kt < 2; kt++) {
      f16x8 pf[2];
#pragma unroll
      for (int nt = 0; nt < 2; nt++) {
        uint4 fr;
        fr.x = U[nt][2 * kt][0];
        fr.y = U[nt][2 * kt][1];
        fr.z = U[nt][2 * kt + 1][0];
        fr.w = U[nt][2 * kt + 1][1];
        pf[nt] = __builtin_bit_cast(f16x8, fr);
      }
      f16x8 vf[8];
#pragma unroll
      for (int dt = 0; dt < 8; dt++) {
        int rd = dt * 16 + l15;
        vf[dt] = *(const f16x8*)(Vc + ((rd * 128 + kt * 64 + q4 * 16) ^ ((rd & 7) << 4)));
      }
      __builtin_amdgcn_s_setprio(1);
#pragma unroll
      for (int dt = 0; dt < 8; dt++)
#pragma unroll
        for (int nt = 0; nt < 2; nt++)
          Ofr[dt][nt] = __builtin_amdgcn_mfma_f32_16x16x32_f16(vf[dt], pf[nt], Ofr[dt][nt], 0, 0, 0);
      __builtin_amdgcn_s_setprio(0);
    }
    __syncthreads();
  }
  // write (m,l) per q-column
  if (q4 == 0) {
#pragma unroll
    for (int nt = 0; nt < 2; nt++) {
      int n = n0 + wid * 32 + nt * 16 + l15;
      float2 ml;
      ml.x = mrun[nt];
      ml.y = lrun[nt];
      *(float2*)(mlbuf + ((size_t)(half * 8 + bh) * 4096 + n) * 2) = ml;
    }
  }
  if (half == 0) {
    float* og = out + (size_t)(b * 256 + hh * 128) * 4096 + n0 + wid * 32;
#pragma unroll
    for (int dt = 0; dt < 8; dt++)
#pragma unroll
      for (int nt = 0; nt < 2; nt++)
#pragma unroll
        for (int j = 0; j < 4; j++) {
          int dd = dt * 16 + q4 * 4 + j;
          og[(size_t)dd * 4096 + nt * 16 + l15] = Ofr[dt][nt][j];
        }
  } else {
    float li[2] = {v_rcp(lrun[0]), v_rcp(lrun[1])};
    unsigned short* og = o1buf + (size_t)bh * 128 * 4096 + n0 + wid * 32;
#pragma unroll
    for (int dt = 0; dt < 8; dt++)
#pragma unroll
      for (int nt = 0; nt < 2; nt++)
#pragma unroll
        for (int j = 0; j < 4; j++) {
          int dd = dt * 16 + q4 * 4 + j;
          og[(size_t)dd * 4096 + nt * 16 + l15] = f2h(Ofr[dt][nt][j] * li[nt]);
        }
  }
}

// ---------- combine the two KV halves (in-place on out) ----------
__global__ __launch_bounds__(256) void k_combine(
    float* __restrict__ out, const unsigned short* __restrict__ o1,
    const float* __restrict__ ml) {
  int tid = blockIdx.x * 256 + threadIdx.x;    // bits: [0:11]=n, [12:14]=dg, [15:17]=bh
  int n = tid & 4095, dg = (tid >> 12) & 7, bh = tid >> 15;
  float2 ml0 = *(const float2*)(ml + ((size_t)bh * 4096 + n) * 2);
  float2 ml1 = *(const float2*)(ml + ((size_t)(8 + bh) * 4096 + n) * 2);
  float ms = fmaxf(ml0.x, ml1.x);
  float a0 = v_exp2(ml0.x - ms);
  float w1 = ml1.y * v_exp2(ml1.x - ms);
  float inv = 1.f / (ml0.y * a0 + w1);
  size_t ob = ((size_t)((bh >> 1) * 256 + (bh & 1) * 128 + dg * 16)) * 4096 + n;
  size_t o1b = ((size_t)(bh * 128 + dg * 16)) * 4096 + n;
#pragma unroll 4
  for (int j = 0; j < 16; j++) {
    float v0 = out[ob + (size_t)j * 4096];
    float v1 = h2f(o1[o1b + (size_t)j * 4096]);
    out[ob + (size_t)j * 4096] = (v0 * a0 + v1 * w1) * inv;
  }
}

extern "C" void kernel_launch(void* const* d_in, const int* in_sizes, int n_in,
                              void* d_out, int out_size, void* d_ws, size_t ws_size,
                              hipStream_t stream) {
  (void)in_sizes; (void)n_in; (void)out_size;
  const float* x  = (const float*)d_in[0];
  const float* qw = (const float*)d_in[1];
  const float* qb = (const float*)d_in[2];
  const float* kw = (const float*)d_in[3];
  const float* kb = (const float*)d_in[4];
  const float* vw = (const float*)d_in[5];
  const float* vb = (const float*)d_in[6];
  char* ws = (char*)d_ws;
  if (ws_size < 37822464) return;
  char* xpad = ws;
  unsigned short* Wq = (unsigned short*)(ws + 11214848);
  unsigned short* Wk = (unsigned short*)(ws + 12394496);
  unsigned short* Wv = (unsigned short*)(ws + 12525568);
  unsigned short* Qb = (unsigned short*)(ws + 12656640);
  unsigned short* Kb = (unsigned short*)(ws + 21045248);
  unsigned short* Vb = (unsigned short*)(ws + 29433856);
  unsigned short* O1 = (unsigned short*)ws;            // reuse xpad after convs (8.4MB)
  float* ML = (float*)(ws + 11214848);                 // reuse Wq after convs (512KB)
  hipMemsetAsync(xpad, 0, 11214848, stream);
  k_prep_x<<<dim3(64, 4), dim3(256), 0, stream>>>(x, xpad);
  k_prep_w<<<dim3(256), dim3(256), 0, stream>>>(qw, kw, vw, Wq, Wk, Wv);
  k_conv_kv<<<dim3(128, 2, 2), dim3(256), 0, stream>>>(xpad, Wk, Wv, kb, vb, Kb, Vb);
  k_conv_q<<<dim3(256), dim3(512), 89600, stream>>>(xpad, Wq, qb, Qb);
  k_attn<<<dim3(512), dim3(256), 0, stream>>>(Qb, Kb, Vb, (float*)d_out, O1, ML);
  k_combine<<<dim3(1024), dim3(256), 0, stream>>>((float*)d_out, O1, ML);
}

// Round 11
// 175.262 us; speedup vs baseline: 1.3627x; 1.0225x over previous
//
#include <hip/hip_runtime.h>
#include <cstdint>

typedef __attribute__((ext_vector_type(8))) _Float16 f16x8;
typedef __attribute__((ext_vector_type(4))) float f32x4;

#define DEV static __device__ __forceinline__

DEV void gld_lds16(void* lds_base, const void* gsrc) {
  __builtin_amdgcn_global_load_lds(
      (const __attribute__((address_space(1))) unsigned int*)gsrc,
      (__attribute__((address_space(3))) unsigned int*)lds_base,
      16, 0, 0);
}
DEV unsigned short f2h(float f) {
  _Float16 h = (_Float16)f;
  return __builtin_bit_cast(unsigned short, h);
}
DEV float h2f(unsigned short u) {
  _Float16 h = __builtin_bit_cast(_Float16, u);
  return (float)h;
}
DEV unsigned pk2h(float a, float b) {
  auto h2 = __builtin_amdgcn_cvt_pkrtz(a, b);
  return __builtin_bit_cast(unsigned, h2);
}
DEV float v_exp2(float x) { float r; asm("v_exp_f32 %0, %1" : "=v"(r) : "v"(x)); return r; }
DEV float v_rcp(float x) { float r; asm("v_rcp_f32 %0, %1" : "=v"(r) : "v"(x)); return r; }

// ---------------- geometry ----------------
// B=4, C=256, H=W=64, N=4096, heads=2, hd=128
// ws layout (bytes):
//   Xpad [4][74][74][256] f16 : 0        .. 11214848   (reused as O1 f16 [8][128][4096] during attn)
//   Wq [3][3][256][256] f16   : 11214848 .. 12394496   (reused as ml buf [2][8][4096][2] f32 during attn)
//   Wk [256][256] f16         : 12394496 .. 12525568
//   Wv [256][256] f16         : 12525568 .. 12656640
//   Q  [8][4096][128] f16     : 12656640 .. 21045248   (pre-scaled by log2e/sqrt(128))
//   K  [8][4096][128] f16     : 21045248 .. 29433856
//   V  [8][128][4096] f16     : 29433856 .. 37822464   (m-permuted per 64-block: s=[m5,m3,m2,m4,m1,m0])

// ---------- prep: x (f32 NCHW) -> Xpad (f16, pixel-major, halo 5) ----------
__global__ __launch_bounds__(256) void k_prep_x(const float* __restrict__ x, char* __restrict__ xpad) {
  __shared__ float xs[32 * 257];
  int h = blockIdx.x, b = blockIdx.y, t = threadIdx.x;
  const float* xb = x + (size_t)b * 1048576 + h * 64;
  for (int half = 0; half < 2; half++) {
    int w0 = half * 32;
    for (int kk = 0; kk < 32; kk++) {
      int flat = kk * 256 + t;       // ci*32 + w
      int ci = flat >> 5, w = flat & 31;
      xs[w * 257 + ci] = xb[ci * 4096 + w0 + w];
    }
    __syncthreads();
    for (int g = 0; g < 4; g++) {
      int w = g * 8 + (t >> 5);
      int cg = t & 31;               // 8-ci chunk
      float v0 = xs[w * 257 + cg * 8 + 0], v1 = xs[w * 257 + cg * 8 + 1];
      float v2 = xs[w * 257 + cg * 8 + 2], v3 = xs[w * 257 + cg * 8 + 3];
      float v4 = xs[w * 257 + cg * 8 + 4], v5 = xs[w * 257 + cg * 8 + 5];
      float v6 = xs[w * 257 + cg * 8 + 6], v7 = xs[w * 257 + cg * 8 + 7];
      uint4 pk;
      pk.x = pk2h(v0, v1);
      pk.y = pk2h(v2, v3);
      pk.z = pk2h(v4, v5);
      pk.w = pk2h(v6, v7);
      *(uint4*)(xpad + ((size_t)((b * 74 + h + 5) * 74) + w0 + w + 5) * 512 + cg * 16) = pk;
    }
    __syncthreads();
  }
}

// ---------- prep: weights -> f16 ----------
__global__ __launch_bounds__(256) void k_prep_w(
    const float* __restrict__ qw, const float* __restrict__ kw, const float* __restrict__ vw,
    unsigned short* __restrict__ Wq, unsigned short* __restrict__ Wk, unsigned short* __restrict__ Wv) {
  int gid = blockIdx.x * 256 + threadIdx.x;   // co*256+ci
  const float* q9 = qw + (size_t)gid * 9;
#pragma unroll
  for (int tp = 0; tp < 9; tp++) Wq[tp * 65536 + gid] = f2h(q9[tp]);
  Wk[gid] = f2h(kw[gid]);
  Wv[gid] = f2h(vw[gid]);
}

// ---------- 1x1 convs: K[bh][m][d], V[bh][d][s(m)] ----------
__global__ __launch_bounds__(256, 2) void k_conv_kv(
    const char* __restrict__ xpad, const unsigned short* __restrict__ Wk,
    const unsigned short* __restrict__ Wv, const float* __restrict__ kb,
    const float* __restrict__ vb, unsigned short* __restrict__ K, unsigned short* __restrict__ V) {
  __shared__ char sm[32768];
  char* Xs = sm;
  char* Ws = sm + 16384;
  int t = threadIdx.x, lane = t & 63, wid = t >> 6, q4 = lane >> 4, l15 = lane & 15;
  int px0 = blockIdx.x * 128;
  int b = px0 >> 12, nn = px0 & 4095;
  int h = blockIdx.y;          // co half / head
  int mode = blockIdx.z;       // 0: K (D[px][co]),  1: V (D[co][px])
  int co0 = h * 128;
  const char* Wsrc = (const char*)(mode ? Wv : Wk);
  int wm = wid & 1, wn = wid >> 1;
  f32x4 acc[4][4] = {};
  for (int c = 0; c < 4; c++) {
    __syncthreads();
    for (int ch = wid * 1024; ch < 16384; ch += 4096) {   // X tile [128px][64ci]
      int o = ch + lane * 16;
      int r = o >> 7;
      int n = nn + r, hh = n >> 6, ww2 = n & 63;
      int col = (o & 127) ^ ((r & 7) << 4);
      gld_lds16(Xs + ch, xpad + ((size_t)((b * 74 + hh + 5) * 74) + ww2 + 5) * 512 + c * 128 + col);
    }
    for (int ch = wid * 1024; ch < 16384; ch += 4096) {   // W tile [128co][64ci]
      int o = ch + lane * 16;
      int r = o >> 7;
      int col = (o & 127) ^ ((r & 7) << 4);
      gld_lds16(Ws + ch, Wsrc + (co0 + r) * 512 + c * 128 + col);
    }
    asm volatile("s_waitcnt vmcnt(0)" ::: "memory");
    __syncthreads();
    int xg = mode ? wn : wm;   // X-frag 64-row group
    int wg = mode ? wm : wn;   // W-frag 64-row group
#pragma unroll
    for (int kt = 0; kt < 2; kt++) {
      f16x8 xf[4], wf[4];
#pragma unroll
      for (int i = 0; i < 4; i++) {
        int rx = xg * 64 + i * 16 + l15;
        xf[i] = *(const f16x8*)(Xs + ((rx * 128 + kt * 64 + q4 * 16) ^ ((rx & 7) << 4)));
        int rw = wg * 64 + i * 16 + l15;
        wf[i] = *(const f16x8*)(Ws + ((rw * 128 + kt * 64 + q4 * 16) ^ ((rw & 7) << 4)));
      }
#pragma unroll
      for (int m = 0; m < 4; m++)
#pragma unroll
        for (int n = 0; n < 4; n++)
          acc[m][n] = mode ? __builtin_amdgcn_mfma_f32_16x16x32_f16(wf[m], xf[n], acc[m][n], 0, 0, 0)
                           : __builtin_amdgcn_mfma_f32_16x16x32_f16(xf[m], wf[n], acc[m][n], 0, 0, 0);
    }
  }
  int bh = b * 2 + h;
  if (mode == 0) {
#pragma unroll
    for (int m = 0; m < 4; m++)
#pragma unroll
      for (int n = 0; n < 4; n++) {
        int dd = wn * 64 + n * 16 + l15;
        float bias = kb[co0 + dd];
#pragma unroll
        for (int j = 0; j < 4; j++) {
          int npix = nn + wm * 64 + m * 16 + q4 * 4 + j;
          K[(size_t)(bh * 4096 + npix) * 128 + dd] = f2h(acc[m][n][j] + bias);
        }
      }
  } else {
#pragma unroll
    for (int m = 0; m < 4; m++)
#pragma unroll
      for (int j = 0; j < 4; j++) {
        int cr = wm * 64 + m * 16 + q4 * 4 + j;
        float bias = vb[co0 + cr];
#pragma unroll
        for (int n = 0; n < 4; n++) {
          // m-permuted storage within each 64-block: m_local = n*16 + l15
          // -> s = (n>>1)*32 + (l15>>2)*8 + (n&1)*4 + (l15&3)
          int pc = nn + wn * 64 + (n >> 1) * 32 + (l15 >> 2) * 8 + (n & 1) * 4 + (l15 & 3);
          V[(size_t)(bh * 128 + cr) * 4096 + pc] = f2h(acc[m][n][j] + bias);
        }
      }
  }
}

// ---------- dilated 3x3 conv sum(SiLU) -> Q[bh][n][d] ----------
// 512-thread blocks (8 waves), 128 px (2 h-rows) per block, grid 256 (XCD-swizzled).
// Bs double-buffered at kw granularity; As single-buffered, re-staged per (kh,c).
__global__ __launch_bounds__(512, 2) void k_conv_q(
    const char* __restrict__ xpad, const unsigned short* __restrict__ Wq,
    const float* __restrict__ qb, unsigned short* __restrict__ Q) {
  extern __shared__ char sm[];                 // 2*16384 + 6*9472 = 89600
  char* As = sm + 32768;
  int t = threadIdx.x, lane = t & 63, wid = t >> 6, q4 = lane >> 4, l15 = lane & 15;
  int fblk = blockIdx.x;
  int g = (fblk & 7) * 32 + (fblk >> 3);       // XCD x owns one (b,ch2) combo
  int h2 = g & 31, b = (g >> 5) & 3, ch2 = g >> 7;
  int h0 = h2 * 2;
  int co0 = ch2 * 128;
  int wn = wid & 1, wq = wid >> 1;
  int hr = wq >> 1, wloc = wq & 1;
  const int dil[3] = {1, 3, 5};
  const char* WqB = (const char*)Wq;
  f32x4 accd[3][2][4] = {};

#define STAGE_B(dstbuf, kh_, c_, kw_)                                             \
  {                                                                               \
    const char* src_ = WqB + (size_t)((kh_)*3 + (kw_)) * 131072 + co0 * 512 + (c_)*128; \
    char* dst_ = (dstbuf);                                                        \
    for (int ch = wid * 1024; ch < 16384; ch += 8192) {                           \
      int o = ch + lane * 16;                                                     \
      int r = o >> 7;                                                             \
      int col = (o & 127) ^ ((r & 7) << 4);                                       \
      gld_lds16(dst_ + ch, src_ + r * 512 + col);                                 \
    }                                                                             \
  }

#define STAGE_A_ROW(slot_, pr_, c_)                                               \
  {                                                                               \
    const char* src_ = xpad + ((size_t)(b * 74 + (pr_)) * 74) * 512 + (c_)*128;   \
    char* dst_ = As + (slot_)*9472;                                               \
    for (int ch = wid * 1024; ch < 9472; ch += 8192) {                            \
      int o = ch + lane * 16;                                                     \
      if (o < 9472) {                                                             \
        int r = o >> 7;                                                           \
        int col = (o & 127) ^ ((r & 7) << 4);                                     \
        gld_lds16(dst_ + ch, src_ + r * 512 + col);                               \
      }                                                                           \
    }                                                                             \
  }

#define STAGE_A(kh_, c_)                                                          \
  {                                                                               \
    if ((kh_) == 1) {                                                             \
      for (int s = 0; s < 2; s++) STAGE_A_ROW(s, h0 + s + 5, c_);                 \
    } else {                                                                      \
      for (int di = 0; di < 3; di++)                                              \
        for (int s = 0; s < 2; s++)                                               \
          STAGE_A_ROW(di * 2 + s, h0 + s + ((kh_)-1) * dil[di] + 5, c_);          \
    }                                                                             \
  }

  // prologue
  STAGE_A(0, 0);
  STAGE_B(sm, 0, 0, 0);
  asm volatile("s_waitcnt vmcnt(0)" ::: "memory");
  __syncthreads();

  int cur = 0;
  for (int kh = 0; kh < 3; kh++) {
    for (int c = 0; c < 4; c++) {
      for (int kw = 0; kw < 3; kw++) {
        // prefetch next unit's weights (fully hidden under this unit's compute)
        int kwn = kw + 1, cn = c, khn = kh;
        if (kwn == 3) { kwn = 0; cn = c + 1; if (cn == 4) { cn = 0; khn = kh + 1; } }
        char* Bnext = cur ? sm : sm + 16384;
        if (khn < 3) STAGE_B(Bnext, khn, cn, kwn);
        // compute unit (kh, c, kw)
        const char* Bc = cur ? sm + 16384 : sm;
        f16x8 bf[4][2];
#pragma unroll
        for (int n = 0; n < 4; n++)
#pragma unroll
          for (int kt = 0; kt < 2; kt++) {
            int rc = wn * 64 + n * 16 + l15;
            bf[n][kt] = *(const f16x8*)(Bc + ((rc * 128 + kt * 64 + q4 * 16) ^ ((rc & 7) << 4)));
          }
#pragma unroll
        for (int di = 0; di < 3; di++) {
          int dw = (kw - 1) * dil[di] + 5;
          const char* Ad = As + (kh == 1 ? hr : di * 2 + hr) * 9472;
          f16x8 af[2][2];
#pragma unroll
          for (int m = 0; m < 2; m++)
#pragma unroll
            for (int kt = 0; kt < 2; kt++) {
              int wp = wloc * 32 + m * 16 + l15 + dw;    // [0,73]
              af[m][kt] = *(const f16x8*)(Ad + ((wp * 128 + kt * 64 + q4 * 16) ^ ((wp & 7) << 4)));
            }
          __builtin_amdgcn_s_setprio(1);
#pragma unroll
          for (int m = 0; m < 2; m++)
#pragma unroll
            for (int n = 0; n < 4; n++)
#pragma unroll
              for (int kt = 0; kt < 2; kt++)
                accd[di][m][n] = __builtin_amdgcn_mfma_f32_16x16x32_f16(af[m][kt], bf[n][kt], accd[di][m][n], 0, 0, 0);
          __builtin_amdgcn_s_setprio(0);
        }
        asm volatile("s_waitcnt vmcnt(0)" ::: "memory");  // drain B prefetch explicitly
        __syncthreads();
        cur ^= 1;
      }
      // re-stage As for next (kh,c)
      int cn2 = c + 1, khn2 = kh;
      if (cn2 == 4) { cn2 = 0; khn2 = kh + 1; }
      if (khn2 < 3) {
        STAGE_A(khn2, cn2);
        asm volatile("s_waitcnt vmcnt(0)" ::: "memory");
        __syncthreads();
      }
    }
  }
#undef STAGE_A
#undef STAGE_A_ROW
#undef STAGE_B
  const float LOG2E = 1.4426950408889634f;
  const float QSCALE = 0.12751879523176862f;  // log2e / sqrt(128)
#pragma unroll
  for (int n = 0; n < 4; n++) {
    float bias = qb[co0 + wn * 64 + n * 16 + l15];
#pragma unroll
    for (int m = 0; m < 2; m++)
#pragma unroll
      for (int j = 0; j < 4; j++) {
        float s = 0.f;
#pragma unroll
        for (int di = 0; di < 3; di++) {
          float v = accd[di][m][n][j] + bias;
          s += v * v_rcp(1.0f + v_exp2(-v * LOG2E));     // SiLU
        }
        int w = wloc * 32 + m * 16 + q4 * 4 + j;
        int npix = (h0 + hr) * 64 + w;
        int dd = wn * 64 + n * 16 + l15;
        Q[((size_t)(b * 2 + ch2) * 4096 + npix) * 128 + dd] = f2h(s * QSCALE);
      }
  }
}

// ---------- flash attention, KV-split in 2 halves: 1D grid 512 (XCD-swizzled), 2 blocks/CU ----------
// R10 semantics exactly; addressing refactored so all DS addresses are
// (loop-invariant VGPR) + (compile-time immediate): main loop unrolled x2 so the
// double-buffer offset is a constant, and per-lane swizzle bases hoisted.
//   kf addr = Tk(kt) + mt*4096,  Tk = (l15*256 + kt*64 + q4*16) ^ (l15<<4)
//     [proof: rm=mt*16+l15 -> rm*256 = mt*4096 + l15*256; rm&15=l15; the XOR
//      term (l15<<4) touches bits 4-7 only; kt*64+q4*16 <= 240 occupies bits 4-7;
//      mt*4096, l15*256 are above bit 7 -> unaffected]
//   vf addr = Uv(kt) + dt*2048,  Uv = (l15*128 + kt*64 + q4*16) ^ ((l15&7)<<4)
// half 0: unnormalized O (f32) -> out; half 1: normalized O (f16) -> o1buf; (m,l) -> mlbuf
__global__ __launch_bounds__(256, 2) void k_attn(
    const unsigned short* __restrict__ Q, const unsigned short* __restrict__ K,
    const unsigned short* __restrict__ V, float* __restrict__ out,
    unsigned short* __restrict__ o1buf, float* __restrict__ mlbuf) {
  __shared__ char sm[65536];   // [0:16K)=K0 [16K:32K)=K1 [32K:48K)=V0 [48K:64K)=V1
  int t = threadIdx.x, lane = t & 63, wid = t >> 6, q4 = lane >> 4, l15 = lane & 15;
  int fblk = blockIdx.x;
  int g = (fblk & 7) * 64 + (fblk >> 3); // XCD swizzle
  int nb = g & 31, bh = (g >> 5) & 7, half = g >> 8;
  int b = bh >> 1, hh = bh & 1;
  int n0 = nb * 128;
  const char* Qg = (const char*)(Q + ((size_t)bh * 4096 + n0) * 128);
  const char* Kg = (const char*)(K + (size_t)bh * 4096 * 128) + half * 524288;
  const char* Vg = (const char*)(V + (size_t)bh * 128 * 4096) + half * 4096;
  // Q fragments direct from global
  f16x8 qf[2][4];
#pragma unroll
  for (int nt = 0; nt < 2; nt++)
#pragma unroll
    for (int kt = 0; kt < 4; kt++) {
      int rn = wid * 32 + nt * 16 + l15;
      qf[nt][kt] = *(const f16x8*)(Qg + (size_t)rn * 256 + kt * 64 + q4 * 16);
    }
  // loop-invariant per-lane DS read bases (hoisted swizzle algebra)
  const char* pT0 = sm + (((l15 * 256 + 0 * 64 + q4 * 16) ^ (l15 << 4)));
  const char* pT1 = sm + (((l15 * 256 + 1 * 64 + q4 * 16) ^ (l15 << 4)));
  const char* pT2 = sm + (((l15 * 256 + 2 * 64 + q4 * 16) ^ (l15 << 4)));
  const char* pT3 = sm + (((l15 * 256 + 3 * 64 + q4 * 16) ^ (l15 << 4)));
  const char* pU0 = sm + 32768 + (((l15 * 128 + 0 * 64 + q4 * 16) ^ ((l15 & 7) << 4)));
  const char* pU1 = sm + 32768 + (((l15 * 128 + 1 * 64 + q4 * 16) ^ ((l15 & 7) << 4)));
  // loop-invariant staging offsets (4 chunks each for K and V)
  int ks[4], vs[4], lch[4];
#pragma unroll
  for (int c2 = 0; c2 < 4; c2++) {
    int ch = wid * 1024 + c2 * 4096;
    int o = ch + lane * 16;
    lch[c2] = ch;
    ks[c2] = o ^ (((o >> 8) & 15) << 4);
    int dd = o >> 7;
    vs[c2] = dd * 8192 + ((o & 127) ^ ((dd & 7) << 4));
  }
  // prologue: stage tile 0 into K0/V0
#pragma unroll
  for (int c2 = 0; c2 < 4; c2++) gld_lds16(sm + lch[c2], Kg + ks[c2]);
#pragma unroll
  for (int c2 = 0; c2 < 4; c2++) gld_lds16(sm + 32768 + lch[c2], Vg + vs[c2]);
  asm volatile("s_waitcnt vmcnt(0)" ::: "memory");
  __syncthreads();
  f32x4 Ofr[8][2] = {};
  float mrun[2] = {-3e38f, -3e38f};
  float lrun[2] = {0.f, 0.f};
  const char* kgp = Kg;   // advances to prefetch-source tile
  const char* vgp = Vg;

  // one iteration body; KB/VB = compile-time byte offsets of the COMPUTE buffers,
  // KBN/VBN = the prefetch-destination buffers. do_pf guarded by caller.
#define ATTN_ITER(KB, VB, KBN, VBN, do_pf)                                          \
  {                                                                                 \
    if (do_pf) {                                                                    \
      kgp += 16384;                                                                 \
      vgp += 128;                                                                   \
      _Pragma("unroll") for (int c2 = 0; c2 < 4; c2++)                              \
          gld_lds16(sm + (KBN) + lch[c2], kgp + ks[c2]);                            \
      _Pragma("unroll") for (int c2 = 0; c2 < 4; c2++)                              \
          gld_lds16(sm + (VBN) + lch[c2], vgp + vs[c2]);                            \
    }                                                                               \
    f32x4 sT[4][2] = {};                                                            \
    _Pragma("unroll") for (int kt = 0; kt < 4; kt++) {                              \
      const char* pT = (kt == 0) ? pT0 : (kt == 1) ? pT1 : (kt == 2) ? pT2 : pT3;   \
      f16x8 kf[4];                                                                  \
      _Pragma("unroll") for (int mt = 0; mt < 4; mt++)                              \
          kf[mt] = *(const f16x8*)(pT + (KB) + mt * 4096);                          \
      __builtin_amdgcn_s_setprio(1);                                                \
      _Pragma("unroll") for (int mt = 0; mt < 4; mt++)                              \
          _Pragma("unroll") for (int nt = 0; nt < 2; nt++)                          \
              sT[mt][nt] = __builtin_amdgcn_mfma_f32_16x16x32_f16(                  \
                  kf[mt], qf[nt][kt], sT[mt][nt], 0, 0, 0);                         \
      __builtin_amdgcn_s_setprio(0);                                                \
    }                                                                               \
    unsigned U[2][4][2];                                                            \
    _Pragma("unroll") for (int nt = 0; nt < 2; nt++) {                              \
      float mx = sT[0][nt][0];                                                      \
      _Pragma("unroll") for (int mt = 0; mt < 4; mt++)                              \
          _Pragma("unroll") for (int j = 0; j < 4; j++) mx = fmaxf(mx, sT[mt][nt][j]); \
      mx = fmaxf(mx, __shfl_xor(mx, 16));                                           \
      mx = fmaxf(mx, __shfl_xor(mx, 32));                                           \
      float mn = mrun[nt];                                                          \
      if (!__all(mx - mn <= 8.f)) {                                                 \
        mn = fmaxf(mrun[nt], mx);                                                   \
        float al = v_exp2(mrun[nt] - mn);                                           \
        mrun[nt] = mn;                                                              \
        lrun[nt] *= al;                                                             \
        _Pragma("unroll") for (int dt = 0; dt < 8; dt++) Ofr[dt][nt] *= al;         \
      }                                                                             \
      float rs = 0.f;                                                               \
      _Pragma("unroll") for (int mt = 0; mt < 4; mt++) {                            \
        float p0 = v_exp2(sT[mt][nt][0] - mn);                                      \
        float p1 = v_exp2(sT[mt][nt][1] - mn);                                      \
        float p2 = v_exp2(sT[mt][nt][2] - mn);                                      \
        float p3 = v_exp2(sT[mt][nt][3] - mn);                                      \
        rs += (p0 + p1) + (p2 + p3);                                                \
        U[nt][mt][0] = pk2h(p0, p1);                                                \
        U[nt][mt][1] = pk2h(p2, p3);                                                \
      }                                                                             \
      rs += __shfl_xor(rs, 16);                                                     \
      rs += __shfl_xor(rs, 32);                                                     \
      lrun[nt] += rs;                                                               \
    }                                                                               \
    _Pragma("unroll") for (int kt = 0; kt < 2; kt++) {                              \
      const char* pU = kt ? pU1 : pU0;                                              \
      f16x8 pf[2];                                                                  \
      _Pragma("unroll") for (int nt = 0; nt < 2; nt++) {                            \
        uint4 fr;                                                                   \
        fr.x = U[nt][2 * kt][0];                                                    \
        fr.y = U[nt][2 * kt][1];                                                    \
        fr.z = U[nt][2 * kt + 1][0];                                                \
        fr.w = U[nt][2 * kt + 1][1];                                                \
        pf[nt] = __builtin_bit_cast(f16x8, fr);                                     \
      }                                                                             \
      f16x8 vf[8];                                                                  \
      _Pragma("unroll") for (int dt = 0; dt < 8; dt++)                              \
          vf[dt] = *(const f16x8*)(pU + ((VB)-32768) + dt * 2048);                  \
      __builtin_amdgcn_s_setprio(1);                                                \
      _Pragma("unroll") for (int dt = 0; dt < 8; dt++)                              \
          _Pragma("unroll") for (int nt = 0; nt < 2; nt++)                          \
              Ofr[dt][nt] = __builtin_amdgcn_mfma_f32_16x16x32_f16(                 \
                  vf[dt], pf[nt], Ofr[dt][nt], 0, 0, 0);                            \
      __builtin_amdgcn_s_setprio(0);                                                \
    }                                                                               \
    __syncthreads();                                                                \
  }

  for (int it2 = 0; it2 < 16; it2++) {
    ATTN_ITER(0, 32768, 16384, 49152, true);            // even it: compute buf0, prefetch buf1
    ATTN_ITER(16384, 49152, 0, 32768, (it2 < 15));      // odd it: compute buf1, prefetch buf0
  }
#undef ATTN_ITER

  // write (m,l) per q-column
  if (q4 == 0) {
#pragma unroll
    for (int nt = 0; nt < 2; nt++) {
      int n = n0 + wid * 32 + nt * 16 + l15;
      float2 ml;
      ml.x = mrun[nt];
      ml.y = lrun[nt];
      *(float2*)(mlbuf + ((size_t)(half * 8 + bh) * 4096 + n) * 2) = ml;
    }
  }
  if (half == 0) {
    float* og = out + (size_t)(b * 256 + hh * 128) * 4096 + n0 + wid * 32;
#pragma unroll
    for (int dt = 0; dt < 8; dt++)
#pragma unroll
      for (int nt = 0; nt < 2; nt++)
#pragma unroll
        for (int j = 0; j < 4; j++) {
          int dd = dt * 16 + q4 * 4 + j;
          og[(size_t)dd * 4096 + nt * 16 + l15] = Ofr[dt][nt][j];
        }
  } else {
    float li[2] = {v_rcp(lrun[0]), v_rcp(lrun[1])};
    unsigned short* og = o1buf + (size_t)bh * 128 * 4096 + n0 + wid * 32;
#pragma unroll
    for (int dt = 0; dt < 8; dt++)
#pragma unroll
      for (int nt = 0; nt < 2; nt++)
#pragma unroll
        for (int j = 0; j < 4; j++) {
          int dd = dt * 16 + q4 * 4 + j;
          og[(size_t)dd * 4096 + nt * 16 + l15] = f2h(Ofr[dt][nt][j] * li[nt]);
        }
  }
}

// ---------- combine the two KV halves (in-place on out) ----------
__global__ __launch_bounds__(256) void k_combine(
    float* __restrict__ out, const unsigned short* __restrict__ o1,
    const float* __restrict__ ml) {
  int tid = blockIdx.x * 256 + threadIdx.x;    // bits: [0:11]=n, [12:14]=dg, [15:17]=bh
  int n = tid & 4095, dg = (tid >> 12) & 7, bh = tid >> 15;
  float2 ml0 = *(const float2*)(ml + ((size_t)bh * 4096 + n) * 2);
  float2 ml1 = *(const float2*)(ml + ((size_t)(8 + bh) * 4096 + n) * 2);
  float ms = fmaxf(ml0.x, ml1.x);
  float a0 = v_exp2(ml0.x - ms);
  float w1 = ml1.y * v_exp2(ml1.x - ms);
  float inv = 1.f / (ml0.y * a0 + w1);
  size_t ob = ((size_t)((bh >> 1) * 256 + (bh & 1) * 128 + dg * 16)) * 4096 + n;
  size_t o1b = ((size_t)(bh * 128 + dg * 16)) * 4096 + n;
#pragma unroll 4
  for (int j = 0; j < 16; j++) {
    float v0 = out[ob + (size_t)j * 4096];
    float v1 = h2f(o1[o1b + (size_t)j * 4096]);
    out[ob + (size_t)j * 4096] = (v0 * a0 + v1 * w1) * inv;
  }
}

extern "C" void kernel_launch(void* const* d_in, const int* in_sizes, int n_in,
                              void* d_out, int out_size, void* d_ws, size_t ws_size,
                              hipStream_t stream) {
  (void)in_sizes; (void)n_in; (void)out_size;
  const float* x  = (const float*)d_in[0];
  const float* qw = (const float*)d_in[1];
  const float* qb = (const float*)d_in[2];
  const float* kw = (const float*)d_in[3];
  const float* kb = (const float*)d_in[4];
  const float* vw = (const float*)d_in[5];
  const float* vb = (const float*)d_in[6];
  char* ws = (char*)d_ws;
  if (ws_size < 37822464) return;
  char* xpad = ws;
  unsigned short* Wq = (unsigned short*)(ws + 11214848);
  unsigned short* Wk = (unsigned short*)(ws + 12394496);
  unsigned short* Wv = (unsigned short*)(ws + 12525568);
  unsigned short* Qb = (unsigned short*)(ws + 12656640);
  unsigned short* Kb = (unsigned short*)(ws + 21045248);
  unsigned short* Vb = (unsigned short*)(ws + 29433856);
  unsigned short* O1 = (unsigned short*)ws;            // reuse xpad after convs (8.4MB)
  float* ML = (float*)(ws + 11214848);                 // reuse Wq after convs (512KB)
  hipMemsetAsync(xpad, 0, 11214848, stream);
  k_prep_x<<<dim3(64, 4), dim3(256), 0, stream>>>(x, xpad);
  k_prep_w<<<dim3(256), dim3(256), 0, stream>>>(qw, kw, vw, Wq, Wk, Wv);
  k_conv_kv<<<dim3(128, 2, 2), dim3(256), 0, stream>>>(xpad, Wk, Wv, kb, vb, Kb, Vb);
  k_conv_q<<<dim3(256), dim3(512), 89600, stream>>>(xpad, Wq, qb, Qb);
  k_attn<<<dim3(512), dim3(256), 0, stream>>>(Qb, Kb, Vb, (float*)d_out, O1, ML);
  k_combine<<<dim3(1024), dim3(256), 0, stream>>>((float*)d_out, O1, ML);
}

// Round 12
// 166.276 us; speedup vs baseline: 1.4363x; 1.0540x over previous
//
#include <hip/hip_runtime.h>
#include <cstdint>

typedef __attribute__((ext_vector_type(8))) _Float16 f16x8;
typedef __attribute__((ext_vector_type(4))) float f32x4;

#define DEV static __device__ __forceinline__

DEV void gld_lds16(void* lds_base, const void* gsrc) {
  __builtin_amdgcn_global_load_lds(
      (const __attribute__((address_space(1))) unsigned int*)gsrc,
      (__attribute__((address_space(3))) unsigned int*)lds_base,
      16, 0, 0);
}
DEV unsigned short f2h(float f) {
  _Float16 h = (_Float16)f;
  return __builtin_bit_cast(unsigned short, h);
}
DEV float h2f(unsigned short u) {
  _Float16 h = __builtin_bit_cast(_Float16, u);
  return (float)h;
}
DEV unsigned pk2h(float a, float b) {
  auto h2 = __builtin_amdgcn_cvt_pkrtz(a, b);
  return __builtin_bit_cast(unsigned, h2);
}
DEV float v_exp2(float x) { float r; asm("v_exp_f32 %0, %1" : "=v"(r) : "v"(x)); return r; }
DEV float v_rcp(float x) { float r; asm("v_rcp_f32 %0, %1" : "=v"(r) : "v"(x)); return r; }

// ---------------- geometry ----------------
// B=4, C=256, H=W=64, N=4096, heads=2, hd=128
// ws layout (bytes):
//   Xpad [4][74][74][256] f16 : 0        .. 11214848   (reused as O1 f16 [8][128][4096] during attn)
//   Wq [3][3][256][256] f16   : 11214848 .. 12394496   (reused as ml buf [2][8][4096][2] f32 during attn)
//   Wk [256][256] f16         : 12394496 .. 12525568
//   Wv [256][256] f16         : 12525568 .. 12656640
//   Q  [8][4096][128] f16     : 12656640 .. 21045248   (pre-scaled by log2e/sqrt(128))
//   K  [8][4096][128] f16     : 21045248 .. 29433856
//   V  [8][128][4096] f16     : 29433856 .. 37822464   (m-permuted per 64-block: s=[m5,m3,m2,m4,m1,m0])

// ---------- prep: x (f32 NCHW) -> Xpad (f16, pixel-major, halo 5) + halo zeroing ----------
__global__ __launch_bounds__(256) void k_prep_x(const float* __restrict__ x, char* __restrict__ xpad) {
  __shared__ float xs[32 * 257];
  int h = blockIdx.x, b = blockIdx.y, t = threadIdx.x;
  // halo zeroing (replaces the 11MB memset): disjoint from all data writes
  uint4 z = {0, 0, 0, 0};
  char* rowbase = xpad + ((size_t)(b * 74 + h + 5) * 74) * 512;
  for (int i = t; i < 320; i += 256) {              // col halo of this data row
    int col = i >> 5, off = (i & 31) * 16;
    int w = (col < 5) ? col : 64 + col;             // cols 0-4, 69-73
    *(uint4*)(rowbase + (size_t)w * 512 + off) = z;
  }
  if (h < 10) {                                     // full halo rows 0-4, 69-73
    int r = (h < 5) ? h : 64 + h;
    char* rb = xpad + ((size_t)(b * 74 + r) * 74) * 512;
    for (int i = t; i < 2368; i += 256) *(uint4*)(rb + (size_t)i * 16) = z;
  }
  const float* xb = x + (size_t)b * 1048576 + h * 64;
  for (int half = 0; half < 2; half++) {
    int w0 = half * 32;
    for (int kk = 0; kk < 32; kk++) {
      int flat = kk * 256 + t;       // ci*32 + w
      int ci = flat >> 5, w = flat & 31;
      xs[w * 257 + ci] = xb[ci * 4096 + w0 + w];
    }
    __syncthreads();
    for (int g = 0; g < 4; g++) {
      int w = g * 8 + (t >> 5);
      int cg = t & 31;               // 8-ci chunk
      float v0 = xs[w * 257 + cg * 8 + 0], v1 = xs[w * 257 + cg * 8 + 1];
      float v2 = xs[w * 257 + cg * 8 + 2], v3 = xs[w * 257 + cg * 8 + 3];
      float v4 = xs[w * 257 + cg * 8 + 4], v5 = xs[w * 257 + cg * 8 + 5];
      float v6 = xs[w * 257 + cg * 8 + 6], v7 = xs[w * 257 + cg * 8 + 7];
      uint4 pk;
      pk.x = pk2h(v0, v1);
      pk.y = pk2h(v2, v3);
      pk.z = pk2h(v4, v5);
      pk.w = pk2h(v6, v7);
      *(uint4*)(xpad + ((size_t)((b * 74 + h + 5) * 74) + w0 + w + 5) * 512 + cg * 16) = pk;
    }
    __syncthreads();
  }
}

// ---------- prep: weights -> f16 ----------
__global__ __launch_bounds__(256) void k_prep_w(
    const float* __restrict__ qw, const float* __restrict__ kw, const float* __restrict__ vw,
    unsigned short* __restrict__ Wq, unsigned short* __restrict__ Wk, unsigned short* __restrict__ Wv) {
  int gid = blockIdx.x * 256 + threadIdx.x;   // co*256+ci
  const float* q9 = qw + (size_t)gid * 9;
#pragma unroll
  for (int tp = 0; tp < 9; tp++) Wq[tp * 65536 + gid] = f2h(q9[tp]);
  Wk[gid] = f2h(kw[gid]);
  Wv[gid] = f2h(vw[gid]);
}

// ---------- 1x1 convs: K[bh][m][d], V[bh][d][s(m)] ----------
// c-loop double-buffered: X/W ping-pong (64KB LDS), staging hidden under compute.
__global__ __launch_bounds__(256, 2) void k_conv_kv(
    const char* __restrict__ xpad, const unsigned short* __restrict__ Wk,
    const unsigned short* __restrict__ Wv, const float* __restrict__ kb,
    const float* __restrict__ vb, unsigned short* __restrict__ K, unsigned short* __restrict__ V) {
  __shared__ char sm[65536];   // buf0: X@0 W@16384 ; buf1: X@32768 W@49152
  int t = threadIdx.x, lane = t & 63, wid = t >> 6, q4 = lane >> 4, l15 = lane & 15;
  int px0 = blockIdx.x * 128;
  int b = px0 >> 12, nn = px0 & 4095;
  int h = blockIdx.y;          // co half / head
  int mode = blockIdx.z;       // 0: K (D[px][co]),  1: V (D[co][px])
  int co0 = h * 128;
  const char* Wsrc = (const char*)(mode ? Wv : Wk);
  int wm = wid & 1, wn = wid >> 1;

#define STAGE_KV(base_, c_)                                                       \
  {                                                                               \
    for (int ch = wid * 1024; ch < 16384; ch += 4096) {                           \
      int o = ch + lane * 16;                                                     \
      int r = o >> 7;                                                             \
      int n = nn + r, hh = n >> 6, ww2 = n & 63;                                  \
      int col = (o & 127) ^ ((r & 7) << 4);                                       \
      gld_lds16((base_) + ch,                                                     \
                xpad + ((size_t)((b * 74 + hh + 5) * 74) + ww2 + 5) * 512 + (c_)*128 + col); \
    }                                                                             \
    for (int ch = wid * 1024; ch < 16384; ch += 4096) {                           \
      int o = ch + lane * 16;                                                     \
      int r = o >> 7;                                                             \
      int col = (o & 127) ^ ((r & 7) << 4);                                       \
      gld_lds16((base_) + 16384 + ch, Wsrc + (co0 + r) * 512 + (c_)*128 + col);   \
    }                                                                             \
  }

  STAGE_KV(sm, 0);
  asm volatile("s_waitcnt vmcnt(0)" ::: "memory");
  __syncthreads();

  f32x4 acc[4][4] = {};
  for (int c = 0; c < 4; c++) {
    char* cb = sm + (c & 1) * 32768;
    if (c < 3) STAGE_KV(sm + ((c & 1) ^ 1) * 32768, c + 1);
    const char* Xs = cb;
    const char* Ws = cb + 16384;
    int xg = mode ? wn : wm;   // X-frag 64-row group
    int wg = mode ? wm : wn;   // W-frag 64-row group
#pragma unroll
    for (int kt = 0; kt < 2; kt++) {
      f16x8 xf[4], wf[4];
#pragma unroll
      for (int i = 0; i < 4; i++) {
        int rx = xg * 64 + i * 16 + l15;
        xf[i] = *(const f16x8*)(Xs + ((rx * 128 + kt * 64 + q4 * 16) ^ ((rx & 7) << 4)));
        int rw = wg * 64 + i * 16 + l15;
        wf[i] = *(const f16x8*)(Ws + ((rw * 128 + kt * 64 + q4 * 16) ^ ((rw & 7) << 4)));
      }
#pragma unroll
      for (int m = 0; m < 4; m++)
#pragma unroll
        for (int n = 0; n < 4; n++)
          acc[m][n] = mode ? __builtin_amdgcn_mfma_f32_16x16x32_f16(wf[m], xf[n], acc[m][n], 0, 0, 0)
                           : __builtin_amdgcn_mfma_f32_16x16x32_f16(xf[m], wf[n], acc[m][n], 0, 0, 0);
    }
    asm volatile("s_waitcnt vmcnt(0)" ::: "memory");
    __syncthreads();
  }
#undef STAGE_KV
  int bh = b * 2 + h;
  if (mode == 0) {
#pragma unroll
    for (int m = 0; m < 4; m++)
#pragma unroll
      for (int n = 0; n < 4; n++) {
        int dd = wn * 64 + n * 16 + l15;
        float bias = kb[co0 + dd];
#pragma unroll
        for (int j = 0; j < 4; j++) {
          int npix = nn + wm * 64 + m * 16 + q4 * 4 + j;
          K[(size_t)(bh * 4096 + npix) * 128 + dd] = f2h(acc[m][n][j] + bias);
        }
      }
  } else {
#pragma unroll
    for (int m = 0; m < 4; m++)
#pragma unroll
      for (int j = 0; j < 4; j++) {
        int cr = wm * 64 + m * 16 + q4 * 4 + j;
        float bias = vb[co0 + cr];
#pragma unroll
        for (int n = 0; n < 4; n++) {
          // m-permuted storage within each 64-block: m_local = n*16 + l15
          // -> s = (n>>1)*32 + (l15>>2)*8 + (n&1)*4 + (l15&3)
          int pc = nn + wn * 64 + (n >> 1) * 32 + (l15 >> 2) * 8 + (n & 1) * 4 + (l15 & 3);
          V[(size_t)(bh * 128 + cr) * 4096 + pc] = f2h(acc[m][n][j] + bias);
        }
      }
  }
}

// ---------- dilated 3x3 conv sum(SiLU) -> Q[bh][n][d] ----------
// 512-thread blocks (8 waves), 128 px (2 h-rows) per block, grid 256 (XCD-swizzled), 1 block/CU.
// Bs double-buffered at kw granularity AND As double-buffered per (kh,c):
// As(next) prefetch issued during the kw==0 unit -> the 11 dedicated As drains disappear.
// LDS: B0@0 B1@16384 A0@32768 A1@89600  (total 146432)
__global__ __launch_bounds__(512, 2) void k_conv_q(
    const char* __restrict__ xpad, const unsigned short* __restrict__ Wq,
    const float* __restrict__ qb, unsigned short* __restrict__ Q) {
  extern __shared__ char sm[];
  int t = threadIdx.x, lane = t & 63, wid = t >> 6, q4 = lane >> 4, l15 = lane & 15;
  int fblk = blockIdx.x;
  int g = (fblk & 7) * 32 + (fblk >> 3);       // XCD x owns one (b,ch2) combo
  int h2 = g & 31, b = (g >> 5) & 3, ch2 = g >> 7;
  int h0 = h2 * 2;
  int co0 = ch2 * 128;
  int wn = wid & 1, wq = wid >> 1;
  int hr = wq >> 1, wloc = wq & 1;
  const int dil[3] = {1, 3, 5};
  const char* WqB = (const char*)Wq;
  f32x4 accd[3][2][4] = {};

#define STAGE_B(dstbuf, kh_, c_, kw_)                                             \
  {                                                                               \
    const char* src_ = WqB + (size_t)((kh_)*3 + (kw_)) * 131072 + co0 * 512 + (c_)*128; \
    char* dst_ = (dstbuf);                                                        \
    for (int ch = wid * 1024; ch < 16384; ch += 8192) {                           \
      int o = ch + lane * 16;                                                     \
      int r = o >> 7;                                                             \
      int col = (o & 127) ^ ((r & 7) << 4);                                       \
      gld_lds16(dst_ + ch, src_ + r * 512 + col);                                 \
    }                                                                             \
  }

#define STAGE_A_ROW(abase_, slot_, pr_, c_)                                       \
  {                                                                               \
    const char* src_ = xpad + ((size_t)(b * 74 + (pr_)) * 74) * 512 + (c_)*128;   \
    char* dst_ = (abase_) + (slot_)*9472;                                         \
    for (int ch = wid * 1024; ch < 9472; ch += 8192) {                            \
      int o = ch + lane * 16;                                                     \
      if (o < 9472) {                                                             \
        int r = o >> 7;                                                           \
        int col = (o & 127) ^ ((r & 7) << 4);                                     \
        gld_lds16(dst_ + ch, src_ + r * 512 + col);                               \
      }                                                                           \
    }                                                                             \
  }

#define STAGE_A(abase_, kh_, c_)                                                  \
  {                                                                               \
    if ((kh_) == 1) {                                                             \
      for (int s = 0; s < 2; s++) STAGE_A_ROW(abase_, s, h0 + s + 5, c_);         \
    } else {                                                                      \
      for (int di = 0; di < 3; di++)                                              \
        for (int s = 0; s < 2; s++)                                               \
          STAGE_A_ROW(abase_, di * 2 + s, h0 + s + ((kh_)-1) * dil[di] + 5, c_);  \
    }                                                                             \
  }

  // prologue
  STAGE_A(sm + 32768, 0, 0);
  STAGE_B(sm, 0, 0, 0);
  asm volatile("s_waitcnt vmcnt(0)" ::: "memory");
  __syncthreads();

  int curB = 0, curA = 0;
  for (int kh = 0; kh < 3; kh++) {
    for (int c = 0; c < 4; c++) {
      // next (kh,c) for the As prefetch
      int cn2 = c + 1, khn2 = kh;
      if (cn2 == 4) { cn2 = 0; khn2 = kh + 1; }
      for (int kw = 0; kw < 3; kw++) {
        // prefetch next unit's weights
        int kwn = kw + 1, cn = c, khn = kh;
        if (kwn == 3) { kwn = 0; cn = c + 1; if (cn == 4) { cn = 0; khn = kh + 1; } }
        char* Bnext = curB ? sm : sm + 16384;
        if (khn < 3) STAGE_B(Bnext, khn, cn, kwn);
        // prefetch next (kh,c)'s As during the kw==0 unit
        if (kw == 0 && khn2 < 3) STAGE_A(sm + 32768 + (curA ^ 1) * 56832, khn2, cn2);
        // compute unit (kh, c, kw)
        const char* Bc = curB ? sm + 16384 : sm;
        const char* Abase = sm + 32768 + curA * 56832;
        f16x8 bf[4][2];
#pragma unroll
        for (int n = 0; n < 4; n++)
#pragma unroll
          for (int kt = 0; kt < 2; kt++) {
            int rc = wn * 64 + n * 16 + l15;
            bf[n][kt] = *(const f16x8*)(Bc + ((rc * 128 + kt * 64 + q4 * 16) ^ ((rc & 7) << 4)));
          }
#pragma unroll
        for (int di = 0; di < 3; di++) {
          int dw = (kw - 1) * dil[di] + 5;
          const char* Ad = Abase + (kh == 1 ? hr : di * 2 + hr) * 9472;
          f16x8 af[2][2];
#pragma unroll
          for (int m = 0; m < 2; m++)
#pragma unroll
            for (int kt = 0; kt < 2; kt++) {
              int wp = wloc * 32 + m * 16 + l15 + dw;    // [0,73]
              af[m][kt] = *(const f16x8*)(Ad + ((wp * 128 + kt * 64 + q4 * 16) ^ ((wp & 7) << 4)));
            }
          __builtin_amdgcn_s_setprio(1);
#pragma unroll
          for (int m = 0; m < 2; m++)
#pragma unroll
            for (int n = 0; n < 4; n++)
#pragma unroll
              for (int kt = 0; kt < 2; kt++)
                accd[di][m][n] = __builtin_amdgcn_mfma_f32_16x16x32_f16(af[m][kt], bf[n][kt], accd[di][m][n], 0, 0, 0);
          __builtin_amdgcn_s_setprio(0);
        }
        asm volatile("s_waitcnt vmcnt(0)" ::: "memory");  // drain prefetches
        __syncthreads();
        curB ^= 1;
      }
      if (khn2 < 3) curA ^= 1;   // flip As at (kh,c) boundary when a prefetch was issued
    }
  }
#undef STAGE_A
#undef STAGE_A_ROW
#undef STAGE_B
  const float LOG2E = 1.4426950408889634f;
  const float QSCALE = 0.12751879523176862f;  // log2e / sqrt(128)
#pragma unroll
  for (int n = 0; n < 4; n++) {
    float bias = qb[co0 + wn * 64 + n * 16 + l15];
#pragma unroll
    for (int m = 0; m < 2; m++)
#pragma unroll
      for (int j = 0; j < 4; j++) {
        float s = 0.f;
#pragma unroll
        for (int di = 0; di < 3; di++) {
          float v = accd[di][m][n][j] + bias;
          s += v * v_rcp(1.0f + v_exp2(-v * LOG2E));     // SiLU
        }
        int w = wloc * 32 + m * 16 + q4 * 4 + j;
        int npix = (h0 + hr) * 64 + w;
        int dd = wn * 64 + n * 16 + l15;
        Q[((size_t)(b * 2 + ch2) * 4096 + npix) * 128 + dd] = f2h(s * QSCALE);
      }
  }
}

// ---------- flash attention, KV-split in 2 halves: 1D grid 512 (XCD-swizzled), 2 blocks/CU ----------
// R11-exact (passing, 90.6us): hoisted DS bases, x2-unrolled loop (buffer offsets as immediates),
// P in registers via V m-permutation; shfl_xor reductions.
// half 0: unnormalized O (f32) -> out; half 1: normalized O (f16) -> o1buf; (m,l) -> mlbuf
__global__ __launch_bounds__(256, 2) void k_attn(
    const unsigned short* __restrict__ Q, const unsigned short* __restrict__ K,
    const unsigned short* __restrict__ V, float* __restrict__ out,
    unsigned short* __restrict__ o1buf, float* __restrict__ mlbuf) {
  __shared__ char sm[65536];   // [0:16K)=K0 [16K:32K)=K1 [32K:48K)=V0 [48K:64K)=V1
  int t = threadIdx.x, lane = t & 63, wid = t >> 6, q4 = lane >> 4, l15 = lane & 15;
  int fblk = blockIdx.x;
  int g = (fblk & 7) * 64 + (fblk >> 3); // XCD swizzle
  int nb = g & 31, bh = (g >> 5) & 7, half = g >> 8;
  int b = bh >> 1, hh = bh & 1;
  int n0 = nb * 128;
  const char* Qg = (const char*)(Q + ((size_t)bh * 4096 + n0) * 128);
  const char* Kg = (const char*)(K + (size_t)bh * 4096 * 128) + half * 524288;
  const char* Vg = (const char*)(V + (size_t)bh * 128 * 4096) + half * 4096;
  // Q fragments direct from global
  f16x8 qf[2][4];
#pragma unroll
  for (int nt = 0; nt < 2; nt++)
#pragma unroll
    for (int kt = 0; kt < 4; kt++) {
      int rn = wid * 32 + nt * 16 + l15;
      qf[nt][kt] = *(const f16x8*)(Qg + (size_t)rn * 256 + kt * 64 + q4 * 16);
    }
  // loop-invariant per-lane DS read bases (hoisted swizzle algebra)
  const char* pT0 = sm + (((l15 * 256 + 0 * 64 + q4 * 16) ^ (l15 << 4)));
  const char* pT1 = sm + (((l15 * 256 + 1 * 64 + q4 * 16) ^ (l15 << 4)));
  const char* pT2 = sm + (((l15 * 256 + 2 * 64 + q4 * 16) ^ (l15 << 4)));
  const char* pT3 = sm + (((l15 * 256 + 3 * 64 + q4 * 16) ^ (l15 << 4)));
  const char* pU0 = sm + 32768 + (((l15 * 128 + 0 * 64 + q4 * 16) ^ ((l15 & 7) << 4)));
  const char* pU1 = sm + 32768 + (((l15 * 128 + 1 * 64 + q4 * 16) ^ ((l15 & 7) << 4)));
  // loop-invariant staging offsets (4 chunks each for K and V)
  int ks[4], vs[4], lch[4];
#pragma unroll
  for (int c2 = 0; c2 < 4; c2++) {
    int ch = wid * 1024 + c2 * 4096;
    int o = ch + lane * 16;
    lch[c2] = ch;
    ks[c2] = o ^ (((o >> 8) & 15) << 4);
    int dd = o >> 7;
    vs[c2] = dd * 8192 + ((o & 127) ^ ((dd & 7) << 4));
  }
  // prologue: stage tile 0 into K0/V0
#pragma unroll
  for (int c2 = 0; c2 < 4; c2++) gld_lds16(sm + lch[c2], Kg + ks[c2]);
#pragma unroll
  for (int c2 = 0; c2 < 4; c2++) gld_lds16(sm + 32768 + lch[c2], Vg + vs[c2]);
  asm volatile("s_waitcnt vmcnt(0)" ::: "memory");
  __syncthreads();
  f32x4 Ofr[8][2] = {};
  float mrun[2] = {-3e38f, -3e38f};
  float lrun[2] = {0.f, 0.f};
  const char* kgp = Kg;   // advances to prefetch-source tile
  const char* vgp = Vg;

#define ATTN_ITER(KB, VB, KBN, VBN, do_pf)                                          \
  {                                                                                 \
    if (do_pf) {                                                                    \
      kgp += 16384;                                                                 \
      vgp += 128;                                                                   \
      _Pragma("unroll") for (int c2 = 0; c2 < 4; c2++)                              \
          gld_lds16(sm + (KBN) + lch[c2], kgp + ks[c2]);                            \
      _Pragma("unroll") for (int c2 = 0; c2 < 4; c2++)                              \
          gld_lds16(sm + (VBN) + lch[c2], vgp + vs[c2]);                            \
    }                                                                               \
    f32x4 sT[4][2] = {};                                                            \
    _Pragma("unroll") for (int kt = 0; kt < 4; kt++) {                              \
      const char* pT = (kt == 0) ? pT0 : (kt == 1) ? pT1 : (kt == 2) ? pT2 : pT3;   \
      f16x8 kf[4];                                                                  \
      _Pragma("unroll") for (int mt = 0; mt < 4; mt++)                              \
          kf[mt] = *(const f16x8*)(pT + (KB) + mt * 4096);                          \
      __builtin_amdgcn_s_setprio(1);                                                \
      _Pragma("unroll") for (int mt = 0; mt < 4; mt++)                              \
          _Pragma("unroll") for (int nt = 0; nt < 2; nt++)                          \
              sT[mt][nt] = __builtin_amdgcn_mfma_f32_16x16x32_f16(                  \
                  kf[mt], qf[nt][kt], sT[mt][nt], 0, 0, 0);                         \
      __builtin_amdgcn_s_setprio(0);                                                \
    }                                                                               \
    unsigned U[2][4][2];                                                            \
    _Pragma("unroll") for (int nt = 0; nt < 2; nt++) {                              \
      float mx = sT[0][nt][0];                                                      \
      _Pragma("unroll") for (int mt = 0; mt < 4; mt++)                              \
          _Pragma("unroll") for (int j = 0; j < 4; j++) mx = fmaxf(mx, sT[mt][nt][j]); \
      mx = fmaxf(mx, __shfl_xor(mx, 16));                                           \
      mx = fmaxf(mx, __shfl_xor(mx, 32));                                           \
      float mn = mrun[nt];                                                          \
      if (!__all(mx - mn <= 8.f)) {                                                 \
        mn = fmaxf(mrun[nt], mx);                                                   \
        float al = v_exp2(mrun[nt] - mn);                                           \
        mrun[nt] = mn;                                                              \
        lrun[nt] *= al;                                                             \
        _Pragma("unroll") for (int dt = 0; dt < 8; dt++) Ofr[dt][nt] *= al;         \
      }                                                                             \
      float rs = 0.f;                                                               \
      _Pragma("unroll") for (int mt = 0; mt < 4; mt++) {                            \
        float p0 = v_exp2(sT[mt][nt][0] - mn);                                      \
        float p1 = v_exp2(sT[mt][nt][1] - mn);                                      \
        float p2 = v_exp2(sT[mt][nt][2] - mn);                                      \
        float p3 = v_exp2(sT[mt][nt][3] - mn);                                      \
        rs += (p0 + p1) + (p2 + p3);                                                \
        U[nt][mt][0] = pk2h(p0, p1);                                                \
        U[nt][mt][1] = pk2h(p2, p3);                                                \
      }                                                                             \
      rs += __shfl_xor(rs, 16);                                                     \
      rs += __shfl_xor(rs, 32);                                                     \
      lrun[nt] += rs;                                                               \
    }                                                                               \
    _Pragma("unroll") for (int kt = 0; kt < 2; kt++) {                              \
      const char* pU = kt ? pU1 : pU0;                                              \
      f16x8 pf[2];                                                                  \
      _Pragma("unroll") for (int nt = 0; nt < 2; nt++) {                            \
        uint4 fr;                                                                   \
        fr.x = U[nt][2 * kt][0];                                                    \
        fr.y = U[nt][2 * kt][1];                                                    \
        fr.z = U[nt][2 * kt + 1][0];                                                \
        fr.w = U[nt][2 * kt + 1][1];                                                \
        pf[nt] = __builtin_bit_cast(f16x8, fr);                                     \
      }                                                                             \
      f16x8 vf[8];                                                                  \
      _Pragma("unroll") for (int dt = 0; dt < 8; dt++)                              \
          vf[dt] = *(const f16x8*)(pU + ((VB)-32768) + dt * 2048);                  \
      __builtin_amdgcn_s_setprio(1);                                                \
      _Pragma("unroll") for (int dt = 0; dt < 8; dt++)                              \
          _Pragma("unroll") for (int nt = 0; nt < 2; nt++)                          \
              Ofr[dt][nt] = __builtin_amdgcn_mfma_f32_16x16x32_f16(                 \
                  vf[dt], pf[nt], Ofr[dt][nt], 0, 0, 0);                            \
      __builtin_amdgcn_s_setprio(0);                                                \
    }                                                                               \
    __syncthreads();                                                                \
  }

  for (int it2 = 0; it2 < 16; it2++) {
    ATTN_ITER(0, 32768, 16384, 49152, true);            // even it: compute buf0, prefetch buf1
    ATTN_ITER(16384, 49152, 0, 32768, (it2 < 15));      // odd it: compute buf1, prefetch buf0
  }
#undef ATTN_ITER

  // write (m,l) per q-column
  if (q4 == 0) {
#pragma unroll
    for (int nt = 0; nt < 2; nt++) {
      int n = n0 + wid * 32 + nt * 16 + l15;
      float2 ml;
      ml.x = mrun[nt];
      ml.y = lrun[nt];
      *(float2*)(mlbuf + ((size_t)(half * 8 + bh) * 4096 + n) * 2) = ml;
    }
  }
  if (half == 0) {
    float* og = out + (size_t)(b * 256 + hh * 128) * 4096 + n0 + wid * 32;
#pragma unroll
    for (int dt = 0; dt < 8; dt++)
#pragma unroll
      for (int nt = 0; nt < 2; nt++)
#pragma unroll
        for (int j = 0; j < 4; j++) {
          int dd = dt * 16 + q4 * 4 + j;
          og[(size_t)dd * 4096 + nt * 16 + l15] = Ofr[dt][nt][j];
        }
  } else {
    float li[2] = {v_rcp(lrun[0]), v_rcp(lrun[1])};
    unsigned short* og = o1buf + (size_t)bh * 128 * 4096 + n0 + wid * 32;
#pragma unroll
    for (int dt = 0; dt < 8; dt++)
#pragma unroll
      for (int nt = 0; nt < 2; nt++)
#pragma unroll
        for (int j = 0; j < 4; j++) {
          int dd = dt * 16 + q4 * 4 + j;
          og[(size_t)dd * 4096 + nt * 16 + l15] = f2h(Ofr[dt][nt][j] * li[nt]);
        }
  }
}

// ---------- combine the two KV halves (in-place on out) ----------
__global__ __launch_bounds__(256) void k_combine(
    float* __restrict__ out, const unsigned short* __restrict__ o1,
    const float* __restrict__ ml) {
  int tid = blockIdx.x * 256 + threadIdx.x;    // bits: [0:11]=n, [12:14]=dg, [15:17]=bh
  int n = tid & 4095, dg = (tid >> 12) & 7, bh = tid >> 15;
  float2 ml0 = *(const float2*)(ml + ((size_t)bh * 4096 + n) * 2);
  float2 ml1 = *(const float2*)(ml + ((size_t)(8 + bh) * 4096 + n) * 2);
  float ms = fmaxf(ml0.x, ml1.x);
  float a0 = v_exp2(ml0.x - ms);
  float w1 = ml1.y * v_exp2(ml1.x - ms);
  float inv = 1.f / (ml0.y * a0 + w1);
  size_t ob = ((size_t)((bh >> 1) * 256 + (bh & 1) * 128 + dg * 16)) * 4096 + n;
  size_t o1b = ((size_t)(bh * 128 + dg * 16)) * 4096 + n;
#pragma unroll 4
  for (int j = 0; j < 16; j++) {
    float v0 = out[ob + (size_t)j * 4096];
    float v1 = h2f(o1[o1b + (size_t)j * 4096]);
    out[ob + (size_t)j * 4096] = (v0 * a0 + v1 * w1) * inv;
  }
}

extern "C" void kernel_launch(void* const* d_in, const int* in_sizes, int n_in,
                              void* d_out, int out_size, void* d_ws, size_t ws_size,
                              hipStream_t stream) {
  (void)in_sizes; (void)n_in; (void)out_size;
  const float* x  = (const float*)d_in[0];
  const float* qw = (const float*)d_in[1];
  const float* qb = (const float*)d_in[2];
  const float* kw = (const float*)d_in[3];
  const float* kb = (const float*)d_in[4];
  const float* vw = (const float*)d_in[5];
  const float* vb = (const float*)d_in[6];
  char* ws = (char*)d_ws;
  if (ws_size < 37822464) return;
  char* xpad = ws;
  unsigned short* Wq = (unsigned short*)(ws + 11214848);
  unsigned short* Wk = (unsigned short*)(ws + 12394496);
  unsigned short* Wv = (unsigned short*)(ws + 12525568);
  unsigned short* Qb = (unsigned short*)(ws + 12656640);
  unsigned short* Kb = (unsigned short*)(ws + 21045248);
  unsigned short* Vb = (unsigned short*)(ws + 29433856);
  unsigned short* O1 = (unsigned short*)ws;            // reuse xpad after convs (8.4MB)
  float* ML = (float*)(ws + 11214848);                 // reuse Wq after convs (512KB)
  k_prep_x<<<dim3(64, 4), dim3(256), 0, stream>>>(x, xpad);
  k_prep_w<<<dim3(256), dim3(256), 0, stream>>>(qw, kw, vw, Wq, Wk, Wv);
  k_conv_kv<<<dim3(128, 2, 2), dim3(256), 0, stream>>>(xpad, Wk, Wv, kb, vb, Kb, Vb);
  k_conv_q<<<dim3(256), dim3(512), 146432, stream>>>(xpad, Wq, qb, Qb);
  k_attn<<<dim3(512), dim3(256), 0, stream>>>(Qb, Kb, Vb, (float*)d_out, O1, ML);
  k_combine<<<dim3(1024), dim3(256), 0, stream>>>((float*)d_out, O1, ML);
}